// Round 1
// baseline (411.121 us; speedup 1.0000x reference)
//
#include <hip/hip_runtime.h>
#include <hip/hip_bf16.h>
#include <cstdint>
#include <cstddef>

#define Bdim 2
#define Tdim 2048
#define Ddim 2048
#define NHq  16
#define NKV  4
#define HD   128
#define SCALE 0.08838834764831845f
// SCALE * log2(e): folded into q inside rope_bf so attention works in exp2 domain
#define QPRESCALE (0.08838834764831845f * 1.4426950408889634f)
#define NEG_INF (-3.0e38f)
// defer-max threshold (log2 domain): e-domain 8 -> 8*log2e ~ 11.5
#define DEFER_THR 11.5f

typedef unsigned short u16;
typedef unsigned int   u32;
typedef __bf16 bf16x8 __attribute__((ext_vector_type(8)));
typedef float  f32x4  __attribute__((ext_vector_type(4)));

__device__ __forceinline__ u16 f2bf(float f) {
    unsigned int u = __float_as_uint(f);
    u += 0x7FFFu + ((u >> 16) & 1u);   // RNE
    return (u16)(u >> 16);
}
// native cast — compiler emits (packed) v_cvt_*_bf16_f32, RNE
__device__ __forceinline__ u16 f2bfn(float f) {
    __bf16 h = (__bf16)f;
    return __builtin_bit_cast(u16, h);
}
__device__ __forceinline__ float bf2f(u16 s) {
    return __uint_as_float(((unsigned int)s) << 16);
}

// async global->LDS, 16B per lane. LDS dest is wave-uniform base + lane*16.
typedef __attribute__((address_space(1))) const u32 gbl_u32;
typedef __attribute__((address_space(3))) u32 lds_u32;
__device__ __forceinline__ void gload16(const void* g, void* l) {
    __builtin_amdgcn_global_load_lds((gbl_u32*)(uintptr_t)g, (lds_u32*)(uintptr_t)l, 16, 0, 0);
}

// ---------------------------------------------------------------------------
// fp32 -> bf16 straight convert for Xq, Xkv. 8 elems/thread.
// ---------------------------------------------------------------------------
__global__ __launch_bounds__(256) void cvt_x(const float* __restrict__ Xq,
                                             const float* __restrict__ Xkv,
                                             u16* __restrict__ oq,
                                             u16* __restrict__ okv)
{
    const size_t NE = (size_t)4096 * 2048 / 8;
    size_t idx = (size_t)blockIdx.x * 256 + threadIdx.x;
    const float* src; u16* dst; size_t off;
    if (idx < NE) { src = Xq;  dst = oq;  off = idx * 8; }
    else          { src = Xkv; dst = okv; off = (idx - NE) * 8; }
    float4 a = *(const float4*)&src[off];
    float4 b = *(const float4*)&src[off + 4];
    ushort4 r0, r1;
    r0.x = f2bf(a.x); r0.y = f2bf(a.y); r0.z = f2bf(a.z); r0.w = f2bf(a.w);
    r1.x = f2bf(b.x); r1.y = f2bf(b.y); r1.z = f2bf(b.z); r1.w = f2bf(b.w);
    *(ushort4*)&dst[off] = r0;
    *(ushort4*)&dst[off + 4] = r1;
}

// ---------------------------------------------------------------------------
// fp32 W[R][C] -> bf16 W^T[C][R], 64x64 LDS tiles. grid (C/64, R/64).
// ---------------------------------------------------------------------------
__global__ __launch_bounds__(256) void cvt_w_t(const float* __restrict__ src,
                                               u16* __restrict__ dst, int R, int C)
{
    __shared__ u16 t[64][72];
    const int r0 = blockIdx.y * 64, c0 = blockIdx.x * 64;
    const int tid = threadIdx.x;
    const int tr = tid >> 4, tc4 = (tid & 15) * 4;
#pragma unroll
    for (int p = 0; p < 4; p++) {
        int r = p * 16 + tr;
        float4 v = *(const float4*)&src[(size_t)(r0 + r) * C + c0 + tc4];
        t[tc4 + 0][r] = f2bf(v.x);
        t[tc4 + 1][r] = f2bf(v.y);
        t[tc4 + 2][r] = f2bf(v.z);
        t[tc4 + 3][r] = f2bf(v.w);
    }
    __syncthreads();
#pragma unroll
    for (int p = 0; p < 4; p++) {
        int cc = p * 16 + tr;
        ushort4 w = *(const ushort4*)&t[cc][tc4];
        *(ushort4*)&dst[(size_t)(c0 + cc) * R + r0 + tc4] = w;
    }
}

// ---------------------------------------------------------------------------
// bf16 MFMA GEMM mainloop (m97 structure)
// ---------------------------------------------------------------------------
__device__ __forceinline__ void bf16_gemm_mainloop(const u16* __restrict__ A,
                                                   const u16* __restrict__ Bt,
                                                   int m0, int n0,
                                                   u16 (&As)[128 * 32],
                                                   u16 (&Bs)[128 * 32],
                                                   f32x4 (&acc)[4][4])
{
    const int tid = threadIdx.x;
    const int wv = tid >> 6, lane = tid & 63;
    const int l15 = lane & 15, quad = lane >> 4;
    const int wr = wv >> 1, wc = wv & 1;

#pragma unroll
    for (int mt = 0; mt < 4; mt++)
#pragma unroll
        for (int nt = 0; nt < 4; nt++) acc[mt][nt] = (f32x4){0.f, 0.f, 0.f, 0.f};

    for (int k0 = 0; k0 < 2048; k0 += 32) {
        __syncthreads();
#pragma unroll
        for (int j = 0; j < 2; j++) {
            int c = wv * 128 + j * 64 + lane;
            const u16* ga = A + (size_t)(m0 + (c >> 2)) * 2048 + k0 + (c & 3) * 8;
            gload16(ga, &As[(wv * 128 + j * 64) * 8]);
            const u16* gb = Bt + (size_t)(n0 + (c >> 2)) * 2048 + k0 + (c & 3) * 8;
            gload16(gb, &Bs[(wv * 128 + j * 64) * 8]);
        }
        __syncthreads();

        bf16x8 af[4], bfr[4];
#pragma unroll
        for (int mt = 0; mt < 4; mt++)
            af[mt] = *(const bf16x8*)&As[(wr * 64 + mt * 16 + l15) * 32 + quad * 8];
#pragma unroll
        for (int nt = 0; nt < 4; nt++)
            bfr[nt] = *(const bf16x8*)&Bs[(wc * 64 + nt * 16 + l15) * 32 + quad * 8];
#pragma unroll
        for (int mt = 0; mt < 4; mt++)
#pragma unroll
            for (int nt = 0; nt < 4; nt++)
                acc[mt][nt] = __builtin_amdgcn_mfma_f32_16x16x32_bf16(af[mt], bfr[nt], acc[mt][nt], 0, 0, 0);
    }
}

// Fused QKV: grid (24, 32).
__global__ __launch_bounds__(256) void qkv_gemm_bf(const u16* __restrict__ Xq,
                                                   const u16* __restrict__ Xkv,
                                                   const u16* __restrict__ Wqt,
                                                   const u16* __restrict__ Wkt,
                                                   const u16* __restrict__ Wvt,
                                                   u16* __restrict__ qraw,
                                                   u16* __restrict__ kraw,
                                                   u16* __restrict__ vt)
{
    __shared__ __align__(16) u16 As[128 * 32];
    __shared__ __align__(16) u16 Bs[128 * 32];
    f32x4 acc[4][4];
    const int bx = blockIdx.x, m0 = blockIdx.y * 128;
    const u16 *A, *Bt; int n0;
    if (bx < 16)      { A = Xq;  Bt = Wqt; n0 = bx * 128; }
    else if (bx < 20) { A = Xkv; Bt = Wkt; n0 = (bx - 16) * 128; }
    else              { A = Xkv; Bt = Wvt; n0 = (bx - 20) * 128; }
    bf16_gemm_mainloop(A, Bt, m0, n0, As, Bs, acc);

    const int tid = threadIdx.x;
    const int wv = tid >> 6, lane = tid & 63;
    const int l15 = lane & 15, quad = lane >> 4;
    const int wr = wv >> 1, wc = wv & 1;

    if (bx < 20) {
        u16* out; int ldw;
        if (bx < 16) { out = qraw; ldw = 2048; }
        else         { out = kraw; ldw = 512; }
#pragma unroll
        for (int mt = 0; mt < 4; mt++)
#pragma unroll
            for (int nt = 0; nt < 4; nt++) {
                int col = n0 + wc * 64 + nt * 16 + l15;
                int r = m0 + wr * 64 + mt * 16 + quad * 4;
#pragma unroll
                for (int reg = 0; reg < 4; reg++)
                    out[(size_t)(r + reg) * ldw + col] = f2bf(acc[mt][nt][reg]);
            }
    } else {
        const int b = m0 >> 11, tb = m0 & 2047;
#pragma unroll
        for (int mt = 0; mt < 4; mt++)
#pragma unroll
            for (int nt = 0; nt < 4; nt++) {
                int col = n0 + wc * 64 + nt * 16 + l15;
                int tloc = tb + wr * 64 + mt * 16 + quad * 4;
                ushort4 w4;
                w4.x = f2bf(acc[mt][nt][0]);
                w4.y = f2bf(acc[mt][nt][1]);
                w4.z = f2bf(acc[mt][nt][2]);
                w4.w = f2bf(acc[mt][nt][3]);
                *(ushort4*)&vt[((size_t)b * 512 + col) * 2048 + tloc] = w4;
            }
    }
}

// Output projection: grid (16, 32).
__global__ __launch_bounds__(256) void oproj_gemm_bf(const u16* __restrict__ attnb,
                                                     const u16* __restrict__ Wot,
                                                     float* __restrict__ out)
{
    __shared__ __align__(16) u16 As[128 * 32];
    __shared__ __align__(16) u16 Bs[128 * 32];
    f32x4 acc[4][4];
    const int m0 = blockIdx.y * 128, n0 = blockIdx.x * 128;
    bf16_gemm_mainloop(attnb, Wot, m0, n0, As, Bs, acc);
    const int tid = threadIdx.x;
    const int wv = tid >> 6, lane = tid & 63;
    const int l15 = lane & 15, quad = lane >> 4;
    const int wr = wv >> 1, wc = wv & 1;
#pragma unroll
    for (int mt = 0; mt < 4; mt++)
#pragma unroll
        for (int nt = 0; nt < 4; nt++) {
            int col = n0 + wc * 64 + nt * 16 + l15;
            int r = m0 + wr * 64 + mt * 16 + quad * 4;
#pragma unroll
            for (int reg = 0; reg < 4; reg++)
                out[(size_t)(r + reg) * 2048 + col] = acc[mt][nt][reg];
        }
}

// In-place RoPE on bf16 q/k. q additionally pre-scaled by SCALE*log2e so
// flash attention's softmax runs in the exp2 domain with no per-score mult.
__global__ __launch_bounds__(256) void rope_bf(u16* __restrict__ q,
                                               u16* __restrict__ k,
                                               const int* __restrict__ qpos,
                                               const int* __restrict__ kvpos)
{
    const int qTh = Bdim * Tdim * NHq * 16;
    int idx = blockIdx.x * 256 + threadIdx.x;
    u16* base; int h4; int pos; float osc;
    if (idx < qTh) {
        int rn = idx >> 4; h4 = (idx & 15) * 4;
        pos = qpos[rn >> 4];
        base = q + (size_t)rn * HD;
        osc = QPRESCALE;
    } else {
        int j = idx - qTh;
        int rn = j >> 4; h4 = (j & 15) * 4;
        pos = kvpos[rn >> 2];
        base = k + (size_t)rn * HD;
        osc = 1.0f;
    }
    ushort4 a = *(const ushort4*)&base[h4];
    ushort4 bvec = *(const ushort4*)&base[h4 + 64];
    u16 av[4] = {a.x, a.y, a.z, a.w};
    u16 bv[4] = {bvec.x, bvec.y, bvec.z, bvec.w};
#pragma unroll
    for (int j = 0; j < 4; j++) {
        float inv_ts = expf(-(float)(h4 + j) * 0.14391156831f);
        float ang = (float)pos * inv_ts;
        float s, c;
        sincosf(ang, &s, &c);
        s *= osc; c *= osc;
        float x1 = bf2f(av[j]), x2 = bf2f(bv[j]);
        av[j] = f2bf(x1 * c - x2 * s);
        bv[j] = f2bf(x2 * c + x1 * s);
    }
    ushort4 ra, rb;
    ra.x = av[0]; ra.y = av[1]; ra.z = av[2]; ra.w = av[3];
    rb.x = bv[0]; rb.y = bv[1]; rb.z = bv[2]; rb.w = bv[3];
    *(ushort4*)&base[h4] = ra;
    *(ushort4*)&base[h4 + 64] = rb;
}

// ---------------------------------------------------------------------------
// Flash attention v3: BQ=128 (4 waves x 32 rows), BKV=64, transposed-S.
// Grid (32 bh, 16 y). Changes vs v2:
//  - double-buffered K/V staging, ONE barrier per KV tile (T3 minimal 2-phase):
//    issue next-tile global_load_lds before computing current tile; the
//    __syncthreads() vmcnt drain lands after a full compute phase.
//  - balanced qt pairing: y<8 -> qt=15-y, y>=8 -> qt=y-8 so round-robin CU
//    pairs sum to constant work (34 iters) instead of 48..20.
//  - exp2-domain softmax (q pre-scaled in rope), defer-max rescale skip (T13),
//    shfl-based alpha/l broadcast (no aArr/lArr LDS), native bf16 converts.
// LDS = 2*16K (K) + 2*16K (V) + 16K (P) = 80 KB exactly -> 2 blocks/CU.
// ---------------------------------------------------------------------------
__global__ __launch_bounds__(256) void flash_attn_v3(const u16* __restrict__ qh,
                                                     const u16* __restrict__ kh,
                                                     const u16* __restrict__ vtg,
                                                     u16* __restrict__ attnb)
{
    // Ks[buf][s][h]: chunk cb = c8 ^ (s&7); addr = s*128 + cb*8 + (h&7)
    __shared__ __align__(16) u16 Ks[2][64 * 128];
    // Vt[buf][h][s]: chunk cb = sb ^ (h&7); addr = h*64 + cb*8 + (s&7)
    __shared__ __align__(16) u16 Vt[2][128 * 64];
    // Ps[m][s]: chunk cb = sb ^ (m&7)
    __shared__ __align__(16) u16 Ps[128 * 64];

    const int yy = blockIdx.y;
    const int qt = (yy < 8) ? (15 - yy) : (yy - 8);   // balanced pairing
    const int bh = blockIdx.x;
    const int b = bh >> 4, n = bh & 15, kvh = n >> 2;
    const int q0 = qt * 128;
    const int tid = threadIdx.x;
    const int wv = tid >> 6, lane = tid & 63;
    const int l15 = lane & 15, quad = lane >> 4;

    const size_t kbase = (size_t)(b * Tdim) * 512 + kvh * 128;
    const size_t vbase = ((size_t)(b * 512 + kvh * 128)) * 2048;
    const int nT = 2 * qt + 2;

    auto stage = [&](int t, int buf) {
        const int s0s = t * 64;
#pragma unroll
        for (int c = 0; c < 4; c++) {
            int j = c * 256 + tid;
            int s = j >> 4;
            int c8 = (j & 15) ^ (s & 7);
            gload16(kh + kbase + (size_t)(s0s + s) * 512 + c8 * 8,
                    &Ks[buf][(c * 256 + wv * 64) * 8]);
            int h = j >> 3;
            int sb = (j & 7) ^ (h & 7);
            gload16(vtg + vbase + (size_t)h * 2048 + s0s + sb * 8,
                    &Vt[buf][(c * 256 + wv * 64) * 8]);
        }
    };

    // issue tile 0 staging first, overlap Q-frag loads with it
    stage(0, 0);

    // ---- Q fragments direct from global (B-operand: n=l15->m, k=quad*8+j->h) ----
    bf16x8 qfrag[2][4];
    {
        const size_t qbase = ((size_t)(b * Tdim + q0 + wv * 32)) * 2048 + n * 128;
#pragma unroll
        for (int mt = 0; mt < 2; mt++)
#pragma unroll
            for (int kt = 0; kt < 4; kt++)
                qfrag[mt][kt] = *(const bf16x8*)(qh + qbase + (size_t)(mt * 16 + l15) * 2048
                                                 + kt * 32 + quad * 8);
    }

    f32x4 Oacc[2][8];
#pragma unroll
    for (int mt = 0; mt < 2; mt++)
#pragma unroll
        for (int ht = 0; ht < 8; ht++) Oacc[mt][ht] = (f32x4){0.f, 0.f, 0.f, 0.f};
    float mrow[2] = {NEG_INF, NEG_INF};
    float lrow[2] = {0.f, 0.f};

    __syncthreads();   // tile 0 staged (vmcnt drained by syncthreads)

    int cur = 0;
    for (int t = 0; t < nT; t++) {
        const int s0 = t * 64;

        // ---- issue next tile's staging into the other buffer (latency hides
        //      under this tile's compute; drained at the end-of-iter barrier) ----
        if (t + 1 < nT) stage(t + 1, cur ^ 1);

        // ---- S^T = K Q^T : tiles nt (s) x mt (m) ----
        f32x4 S[2][4];
#pragma unroll
        for (int mt = 0; mt < 2; mt++)
#pragma unroll
            for (int nt = 0; nt < 4; nt++) S[mt][nt] = (f32x4){0.f, 0.f, 0.f, 0.f};
#pragma unroll
        for (int kt = 0; kt < 4; kt++) {
            bf16x8 kf[4];
#pragma unroll
            for (int nt = 0; nt < 4; nt++) {
                int s = nt * 16 + l15;
                int cb = (kt * 4 + quad) ^ (s & 7);
                kf[nt] = *(const bf16x8*)&Ks[cur][s * 128 + cb * 8];
            }
#pragma unroll
            for (int mt = 0; mt < 2; mt++)
#pragma unroll
                for (int nt = 0; nt < 4; nt++)
                    S[mt][nt] = __builtin_amdgcn_mfma_f32_16x16x32_bf16(kf[nt], qfrag[mt][kt], S[mt][nt], 0, 0, 0);
        }

        // ---- online softmax, exp2 domain (lane owns one m per mt) ----
        const bool domask = (t >= nT - 2);
#pragma unroll
        for (int mt = 0; mt < 2; mt++) {
            const int m_l = wv * 32 + mt * 16 + l15;
            const int mg = q0 + m_l;
            float sv[16];
            float mx = NEG_INF;
#pragma unroll
            for (int nt = 0; nt < 4; nt++)
#pragma unroll
                for (int r = 0; r < 4; r++) {
                    float vv = S[mt][nt][r];          // already scaled (q pre-scale)
                    if (domask) {
                        int sg = s0 + nt * 16 + quad * 4 + r;
                        if (sg > mg) vv = NEG_INF;
                    }
                    sv[nt * 4 + r] = vv;
                    mx = fmaxf(mx, vv);
                }
            mx = fmaxf(mx, __shfl_xor(mx, 16));
            mx = fmaxf(mx, __shfl_xor(mx, 32));
            const float mOld = mrow[mt];
            // T13 defer-max: if no row of this wave grew past THR, keep mOld
            const bool skip = __all(mx <= mOld + DEFER_THR);
            const float mNew = skip ? mOld : fmaxf(mOld, mx);
            float ps = 0.f;
#pragma unroll
            for (int i = 0; i < 16; i++) {
                float p = __builtin_amdgcn_exp2f(sv[i] - mNew);  // masked -> 0
                sv[i] = p;
                ps += p;
            }
            ps += __shfl_xor(ps, 16);
            ps += __shfl_xor(ps, 32);
            if (skip) {
                lrow[mt] += ps;
            } else {
                float alpha = __builtin_amdgcn_exp2f(mOld - mNew);
                mrow[mt] = mNew;
                lrow[mt] = lrow[mt] * alpha + ps;
                // rescale O: lane needs alpha of rows quad*4+r (held by lane quad*4+r)
                float a0 = __shfl(alpha, quad * 4 + 0);
                float a1 = __shfl(alpha, quad * 4 + 1);
                float a2 = __shfl(alpha, quad * 4 + 2);
                float a3 = __shfl(alpha, quad * 4 + 3);
#pragma unroll
                for (int ht = 0; ht < 8; ht++) {
                    Oacc[mt][ht][0] *= a0;
                    Oacc[mt][ht][1] *= a1;
                    Oacc[mt][ht][2] *= a2;
                    Oacc[mt][ht][3] *= a3;
                }
            }
            // P write: per nt, 4 contiguous s -> ds_write_b64 (same-wave rows only)
#pragma unroll
            for (int nt = 0; nt < 4; nt++) {
                int sb = nt * 2 + (quad >> 1);
                int cb = sb ^ (m_l & 7);
                ushort4 pw;
                pw.x = f2bfn(sv[nt * 4 + 0]);
                pw.y = f2bfn(sv[nt * 4 + 1]);
                pw.z = f2bfn(sv[nt * 4 + 2]);
                pw.w = f2bfn(sv[nt * 4 + 3]);
                *(ushort4*)&Ps[m_l * 64 + cb * 8 + (quad & 1) * 4] = pw;
            }
        }

        // ---- O += P V ----
#pragma unroll
        for (int k2 = 0; k2 < 2; k2++) {
            bf16x8 pf[2];
#pragma unroll
            for (int mt = 0; mt < 2; mt++) {
                int m_l = wv * 32 + mt * 16 + l15;
                int cb = (k2 * 4 + quad) ^ (m_l & 7);
                pf[mt] = *(const bf16x8*)&Ps[m_l * 64 + cb * 8];
            }
#pragma unroll
            for (int ht = 0; ht < 8; ht++) {
                int h = ht * 16 + l15;
                int cb = (k2 * 4 + quad) ^ (h & 7);
                bf16x8 vf = *(const bf16x8*)&Vt[cur][h * 64 + cb * 8];
#pragma unroll
                for (int mt = 0; mt < 2; mt++)
                    Oacc[mt][ht] = __builtin_amdgcn_mfma_f32_16x16x32_bf16(pf[mt], vf, Oacc[mt][ht], 0, 0, 0);
            }
        }

        __syncthreads();   // drains next-tile vmcnt + all waves done reading buf[cur]
        cur ^= 1;
    }

    // ---- epilogue: l broadcast via shfl (row quad*4+r held by lane quad*4+r) ----
#pragma unroll
    for (int mt = 0; mt < 2; mt++) {
        f32x4 inv;
#pragma unroll
        for (int r = 0; r < 4; r++)
            inv[r] = 1.0f / __shfl(lrow[mt], quad * 4 + r);
        int mg0 = q0 + wv * 32 + mt * 16 + quad * 4;
        u16* dst0 = attnb + ((size_t)(b * Tdim + mg0)) * 2048 + n * 128 + l15;
#pragma unroll
        for (int ht = 0; ht < 8; ht++) {
#pragma unroll
            for (int r = 0; r < 4; r++)
                dst0[(size_t)r * 2048 + ht * 16] = f2bfn(Oacc[mt][ht][r] * inv[r]);
        }
    }
}

extern "C" void kernel_launch(void* const* d_in, const int* in_sizes, int n_in,
                              void* d_out, int out_size, void* d_ws, size_t ws_size,
                              hipStream_t stream) {
    const float* Xq    = (const float*)d_in[0];
    const float* Xkv   = (const float*)d_in[1];
    const int*   qpos  = (const int*)d_in[2];
    const int*   kvpos = (const int*)d_in[3];
    const float* Wq    = (const float*)d_in[4];
    const float* Wk    = (const float*)d_in[5];
    const float* Wv    = (const float*)d_in[6];
    const float* Wo    = (const float*)d_in[7];
    float* out = (float*)d_out;

    char* w = (char*)d_ws;
    u16* xq_bf = (u16*)(w);                    // 16 MB
    u16* xkv_bf= (u16*)(w + (16u << 20));      // 16 MB
    u16* qraw  = (u16*)(w + (32u << 20));      // 16 MB (roped in place)
    u16* kraw  = (u16*)(w + (48u << 20));      //  4 MB (roped in place)
    u16* vt    = (u16*)(w + (52u << 20));      //  4 MB [(b*4+kvh)*128+h][2048]
    u16* wq_t  = (u16*)(w + (56u << 20));      //  8 MB
    u16* wk_t  = (u16*)(w + (64u << 20));      //  2 MB
    u16* wv_t  = (u16*)(w + (66u << 20));      //  2 MB
    u16* wo_t  = (u16*)(w + (68u << 20));      //  8 MB
    u16* attnb = (u16*)(w);                    // aliases xq_bf (dead by then)

    cvt_x<<<8192, 256, 0, stream>>>(Xq, Xkv, xq_bf, xkv_bf);
    cvt_w_t<<<dim3(32, 32), 256, 0, stream>>>(Wq, wq_t, 2048, 2048);
    cvt_w_t<<<dim3(8, 32),  256, 0, stream>>>(Wk, wk_t, 2048, 512);
    cvt_w_t<<<dim3(8, 32),  256, 0, stream>>>(Wv, wv_t, 2048, 512);
    cvt_w_t<<<dim3(32, 32), 256, 0, stream>>>(Wo, wo_t, 2048, 2048);
    qkv_gemm_bf<<<dim3(24, 32), 256, 0, stream>>>(xq_bf, xkv_bf, wq_t, wk_t, wv_t,
                                                  qraw, kraw, vt);
    rope_bf<<<5120, 256, 0, stream>>>(qraw, kraw, qpos, kvpos);
    flash_attn_v3<<<dim3(32, 16), 256, 0, stream>>>(qraw, kraw, vt, attnb);
    oproj_gemm_bf<<<dim3(16, 32), 256, 0, stream>>>(attnb, wo_t, out);
}

// Round 2
// 404.418 us; speedup vs baseline: 1.0166x; 1.0166x over previous
//
#include <hip/hip_runtime.h>
#include <hip/hip_bf16.h>
#include <cstdint>
#include <cstddef>

#define Bdim 2
#define Tdim 2048
#define Ddim 2048
#define NHq  16
#define NKV  4
#define HD   128
#define SCALE 0.08838834764831845f
// SCALE * log2(e): folded into q inside rope_bf so attention works in exp2 domain
#define QPRESCALE (0.08838834764831845f * 1.4426950408889634f)
#define NEG_INF (-3.0e38f)
// defer-max threshold (log2 domain): e-domain 8 -> 8*log2e ~ 11.5
#define DEFER_THR 11.5f

typedef unsigned short u16;
typedef unsigned int   u32;
typedef __bf16 bf16x8 __attribute__((ext_vector_type(8)));
typedef float  f32x4  __attribute__((ext_vector_type(4)));

__device__ __forceinline__ u16 f2bf(float f) {
    unsigned int u = __float_as_uint(f);
    u += 0x7FFFu + ((u >> 16) & 1u);   // RNE
    return (u16)(u >> 16);
}
// native cast — compiler emits (packed) v_cvt_*_bf16_f32, RNE
__device__ __forceinline__ u16 f2bfn(float f) {
    __bf16 h = (__bf16)f;
    return __builtin_bit_cast(u16, h);
}
__device__ __forceinline__ float bf2f(u16 s) {
    return __uint_as_float(((unsigned int)s) << 16);
}

// ---------------------------------------------------------------------------
// cross-quad (xor16 / xor32) wave reductions.
// gfx950 v_permlane{16,32}_swap_b32 are VALU ops (~4cy) vs __shfl_xor's
// ds_bpermute (LDS pipe, ~60-120cy latency). swap(x,x) yields both halves:
//   permlane16_swap(x,x) -> r0 = rows{0,0,2,2}, r1 = rows{1,1,3,3}
//   permlane32_swap(x,x) -> r0 = rows{0,1,0,1}, r1 = rows{2,3,2,3}
// so op(r0,r1) is the butterfly stage for all lanes.
// ---------------------------------------------------------------------------
#if __has_builtin(__builtin_amdgcn_permlane16_swap) && __has_builtin(__builtin_amdgcn_permlane32_swap)
#define HAVE_PERMLANE_SWAP 1
#endif

__device__ __forceinline__ float quad_reduce_max(float v) {
#ifdef HAVE_PERMLANE_SWAP
    auto r = __builtin_amdgcn_permlane16_swap(__float_as_uint(v), __float_as_uint(v), false, false);
    float m = fmaxf(__uint_as_float(r[0]), __uint_as_float(r[1]));
    auto r2 = __builtin_amdgcn_permlane32_swap(__float_as_uint(m), __float_as_uint(m), false, false);
    return fmaxf(__uint_as_float(r2[0]), __uint_as_float(r2[1]));
#else
    v = fmaxf(v, __shfl_xor(v, 16));
    return fmaxf(v, __shfl_xor(v, 32));
#endif
}
__device__ __forceinline__ float quad_reduce_sum(float v) {
#ifdef HAVE_PERMLANE_SWAP
    auto r = __builtin_amdgcn_permlane16_swap(__float_as_uint(v), __float_as_uint(v), false, false);
    float s = __uint_as_float(r[0]) + __uint_as_float(r[1]);
    auto r2 = __builtin_amdgcn_permlane32_swap(__float_as_uint(s), __float_as_uint(s), false, false);
    return __uint_as_float(r2[0]) + __uint_as_float(r2[1]);
#else
    v += __shfl_xor(v, 16);
    return v + __shfl_xor(v, 32);
#endif
}

// depth-4 trees (compiler won't reassociate FP chains without fast-math)
__device__ __forceinline__ float tree_max16(const float (&s)[16]) {
    float a0 = fmaxf(s[0], s[1]),  a1 = fmaxf(s[2], s[3]);
    float a2 = fmaxf(s[4], s[5]),  a3 = fmaxf(s[6], s[7]);
    float a4 = fmaxf(s[8], s[9]),  a5 = fmaxf(s[10], s[11]);
    float a6 = fmaxf(s[12], s[13]), a7 = fmaxf(s[14], s[15]);
    float b0 = fmaxf(a0, a1), b1 = fmaxf(a2, a3);
    float b2 = fmaxf(a4, a5), b3 = fmaxf(a6, a7);
    return fmaxf(fmaxf(b0, b1), fmaxf(b2, b3));
}
__device__ __forceinline__ float tree_sum16(const float (&s)[16]) {
    float a0 = s[0] + s[1],  a1 = s[2] + s[3];
    float a2 = s[4] + s[5],  a3 = s[6] + s[7];
    float a4 = s[8] + s[9],  a5 = s[10] + s[11];
    float a6 = s[12] + s[13], a7 = s[14] + s[15];
    float b0 = a0 + a1, b1 = a2 + a3, b2 = a4 + a5, b3 = a6 + a7;
    return (b0 + b1) + (b2 + b3);
}

// async global->LDS, 16B per lane. LDS dest is wave-uniform base + lane*16.
typedef __attribute__((address_space(1))) const u32 gbl_u32;
typedef __attribute__((address_space(3))) u32 lds_u32;
__device__ __forceinline__ void gload16(const void* g, void* l) {
    __builtin_amdgcn_global_load_lds((gbl_u32*)(uintptr_t)g, (lds_u32*)(uintptr_t)l, 16, 0, 0);
}

// ---------------------------------------------------------------------------
// fp32 -> bf16 straight convert for Xq, Xkv. 8 elems/thread.
// ---------------------------------------------------------------------------
__global__ __launch_bounds__(256) void cvt_x(const float* __restrict__ Xq,
                                             const float* __restrict__ Xkv,
                                             u16* __restrict__ oq,
                                             u16* __restrict__ okv)
{
    const size_t NE = (size_t)4096 * 2048 / 8;
    size_t idx = (size_t)blockIdx.x * 256 + threadIdx.x;
    const float* src; u16* dst; size_t off;
    if (idx < NE) { src = Xq;  dst = oq;  off = idx * 8; }
    else          { src = Xkv; dst = okv; off = (idx - NE) * 8; }
    float4 a = *(const float4*)&src[off];
    float4 b = *(const float4*)&src[off + 4];
    ushort4 r0, r1;
    r0.x = f2bf(a.x); r0.y = f2bf(a.y); r0.z = f2bf(a.z); r0.w = f2bf(a.w);
    r1.x = f2bf(b.x); r1.y = f2bf(b.y); r1.z = f2bf(b.z); r1.w = f2bf(b.w);
    *(ushort4*)&dst[off] = r0;
    *(ushort4*)&dst[off + 4] = r1;
}

// ---------------------------------------------------------------------------
// fp32 W[R][C] -> bf16 W^T[C][R], 64x64 LDS tiles. grid (C/64, R/64).
// ---------------------------------------------------------------------------
__global__ __launch_bounds__(256) void cvt_w_t(const float* __restrict__ src,
                                               u16* __restrict__ dst, int R, int C)
{
    __shared__ u16 t[64][72];
    const int r0 = blockIdx.y * 64, c0 = blockIdx.x * 64;
    const int tid = threadIdx.x;
    const int tr = tid >> 4, tc4 = (tid & 15) * 4;
#pragma unroll
    for (int p = 0; p < 4; p++) {
        int r = p * 16 + tr;
        float4 v = *(const float4*)&src[(size_t)(r0 + r) * C + c0 + tc4];
        t[tc4 + 0][r] = f2bf(v.x);
        t[tc4 + 1][r] = f2bf(v.y);
        t[tc4 + 2][r] = f2bf(v.z);
        t[tc4 + 3][r] = f2bf(v.w);
    }
    __syncthreads();
#pragma unroll
    for (int p = 0; p < 4; p++) {
        int cc = p * 16 + tr;
        ushort4 w = *(const ushort4*)&t[cc][tc4];
        *(ushort4*)&dst[(size_t)(c0 + cc) * R + r0 + tc4] = w;
    }
}

// ---------------------------------------------------------------------------
// bf16 MFMA GEMM mainloop (m97 structure)
// ---------------------------------------------------------------------------
__device__ __forceinline__ void bf16_gemm_mainloop(const u16* __restrict__ A,
                                                   const u16* __restrict__ Bt,
                                                   int m0, int n0,
                                                   u16 (&As)[128 * 32],
                                                   u16 (&Bs)[128 * 32],
                                                   f32x4 (&acc)[4][4])
{
    const int tid = threadIdx.x;
    const int wv = tid >> 6, lane = tid & 63;
    const int l15 = lane & 15, quad = lane >> 4;
    const int wr = wv >> 1, wc = wv & 1;

#pragma unroll
    for (int mt = 0; mt < 4; mt++)
#pragma unroll
        for (int nt = 0; nt < 4; nt++) acc[mt][nt] = (f32x4){0.f, 0.f, 0.f, 0.f};

    for (int k0 = 0; k0 < 2048; k0 += 32) {
        __syncthreads();
#pragma unroll
        for (int j = 0; j < 2; j++) {
            int c = wv * 128 + j * 64 + lane;
            const u16* ga = A + (size_t)(m0 + (c >> 2)) * 2048 + k0 + (c & 3) * 8;
            gload16(ga, &As[(wv * 128 + j * 64) * 8]);
            const u16* gb = Bt + (size_t)(n0 + (c >> 2)) * 2048 + k0 + (c & 3) * 8;
            gload16(gb, &Bs[(wv * 128 + j * 64) * 8]);
        }
        __syncthreads();

        bf16x8 af[4], bfr[4];
#pragma unroll
        for (int mt = 0; mt < 4; mt++)
            af[mt] = *(const bf16x8*)&As[(wr * 64 + mt * 16 + l15) * 32 + quad * 8];
#pragma unroll
        for (int nt = 0; nt < 4; nt++)
            bfr[nt] = *(const bf16x8*)&Bs[(wc * 64 + nt * 16 + l15) * 32 + quad * 8];
#pragma unroll
        for (int mt = 0; mt < 4; mt++)
#pragma unroll
            for (int nt = 0; nt < 4; nt++)
                acc[mt][nt] = __builtin_amdgcn_mfma_f32_16x16x32_bf16(af[mt], bfr[nt], acc[mt][nt], 0, 0, 0);
    }
}

// Fused QKV: grid (24, 32).
__global__ __launch_bounds__(256) void qkv_gemm_bf(const u16* __restrict__ Xq,
                                                   const u16* __restrict__ Xkv,
                                                   const u16* __restrict__ Wqt,
                                                   const u16* __restrict__ Wkt,
                                                   const u16* __restrict__ Wvt,
                                                   u16* __restrict__ qraw,
                                                   u16* __restrict__ kraw,
                                                   u16* __restrict__ vt)
{
    __shared__ __align__(16) u16 As[128 * 32];
    __shared__ __align__(16) u16 Bs[128 * 32];
    f32x4 acc[4][4];
    const int bx = blockIdx.x, m0 = blockIdx.y * 128;
    const u16 *A, *Bt; int n0;
    if (bx < 16)      { A = Xq;  Bt = Wqt; n0 = bx * 128; }
    else if (bx < 20) { A = Xkv; Bt = Wkt; n0 = (bx - 16) * 128; }
    else              { A = Xkv; Bt = Wvt; n0 = (bx - 20) * 128; }
    bf16_gemm_mainloop(A, Bt, m0, n0, As, Bs, acc);

    const int tid = threadIdx.x;
    const int wv = tid >> 6, lane = tid & 63;
    const int l15 = lane & 15, quad = lane >> 4;
    const int wr = wv >> 1, wc = wv & 1;

    if (bx < 20) {
        u16* out; int ldw;
        if (bx < 16) { out = qraw; ldw = 2048; }
        else         { out = kraw; ldw = 512; }
#pragma unroll
        for (int mt = 0; mt < 4; mt++)
#pragma unroll
            for (int nt = 0; nt < 4; nt++) {
                int col = n0 + wc * 64 + nt * 16 + l15;
                int r = m0 + wr * 64 + mt * 16 + quad * 4;
#pragma unroll
                for (int reg = 0; reg < 4; reg++)
                    out[(size_t)(r + reg) * ldw + col] = f2bf(acc[mt][nt][reg]);
            }
    } else {
        const int b = m0 >> 11, tb = m0 & 2047;
#pragma unroll
        for (int mt = 0; mt < 4; mt++)
#pragma unroll
            for (int nt = 0; nt < 4; nt++) {
                int col = n0 + wc * 64 + nt * 16 + l15;
                int tloc = tb + wr * 64 + mt * 16 + quad * 4;
                ushort4 w4;
                w4.x = f2bf(acc[mt][nt][0]);
                w4.y = f2bf(acc[mt][nt][1]);
                w4.z = f2bf(acc[mt][nt][2]);
                w4.w = f2bf(acc[mt][nt][3]);
                *(ushort4*)&vt[((size_t)b * 512 + col) * 2048 + tloc] = w4;
            }
    }
}

// Output projection: grid (16, 32).
__global__ __launch_bounds__(256) void oproj_gemm_bf(const u16* __restrict__ attnb,
                                                     const u16* __restrict__ Wot,
                                                     float* __restrict__ out)
{
    __shared__ __align__(16) u16 As[128 * 32];
    __shared__ __align__(16) u16 Bs[128 * 32];
    f32x4 acc[4][4];
    const int m0 = blockIdx.y * 128, n0 = blockIdx.x * 128;
    bf16_gemm_mainloop(attnb, Wot, m0, n0, As, Bs, acc);
    const int tid = threadIdx.x;
    const int wv = tid >> 6, lane = tid & 63;
    const int l15 = lane & 15, quad = lane >> 4;
    const int wr = wv >> 1, wc = wv & 1;
#pragma unroll
    for (int mt = 0; mt < 4; mt++)
#pragma unroll
        for (int nt = 0; nt < 4; nt++) {
            int col = n0 + wc * 64 + nt * 16 + l15;
            int r = m0 + wr * 64 + mt * 16 + quad * 4;
#pragma unroll
            for (int reg = 0; reg < 4; reg++)
                out[(size_t)(r + reg) * 2048 + col] = acc[mt][nt][reg];
        }
}

// In-place RoPE on bf16 q/k. q additionally pre-scaled by SCALE*log2e so
// flash attention's softmax runs in the exp2 domain with no per-score mult.
__global__ __launch_bounds__(256) void rope_bf(u16* __restrict__ q,
                                               u16* __restrict__ k,
                                               const int* __restrict__ qpos,
                                               const int* __restrict__ kvpos)
{
    const int qTh = Bdim * Tdim * NHq * 16;
    int idx = blockIdx.x * 256 + threadIdx.x;
    u16* base; int h4; int pos; float osc;
    if (idx < qTh) {
        int rn = idx >> 4; h4 = (idx & 15) * 4;
        pos = qpos[rn >> 4];
        base = q + (size_t)rn * HD;
        osc = QPRESCALE;
    } else {
        int j = idx - qTh;
        int rn = j >> 4; h4 = (j & 15) * 4;
        pos = kvpos[rn >> 2];
        base = k + (size_t)rn * HD;
        osc = 1.0f;
    }
    ushort4 a = *(const ushort4*)&base[h4];
    ushort4 bvec = *(const ushort4*)&base[h4 + 64];
    u16 av[4] = {a.x, a.y, a.z, a.w};
    u16 bv[4] = {bvec.x, bvec.y, bvec.z, bvec.w};
#pragma unroll
    for (int j = 0; j < 4; j++) {
        float inv_ts = expf(-(float)(h4 + j) * 0.14391156831f);
        float ang = (float)pos * inv_ts;
        float s, c;
        sincosf(ang, &s, &c);
        s *= osc; c *= osc;
        float x1 = bf2f(av[j]), x2 = bf2f(bv[j]);
        av[j] = f2bf(x1 * c - x2 * s);
        bv[j] = f2bf(x2 * c + x1 * s);
    }
    ushort4 ra, rb;
    ra.x = av[0]; ra.y = av[1]; ra.z = av[2]; ra.w = av[3];
    rb.x = bv[0]; rb.y = bv[1]; rb.z = bv[2]; rb.w = bv[3];
    *(ushort4*)&base[h4] = ra;
    *(ushort4*)&base[h4 + 64] = rb;
}

// ---------------------------------------------------------------------------
// Flash attention v4: BQ=128 (4 waves x 32 rows), BKV=64, transposed-S.
// Grid (32 bh, 16 y). v3 + softmax critical-chain cut:
//  - permlane16/32_swap butterflies (VALU) replace ds_bpermute shfl_xor
//  - depth-4 trees for 16-elem max/sum (were 16-deep serial chains)
//  - both mt lanes of the chain processed phase-by-phase (2-way ILP)
//  - P LDS-writes issued before the sum reduction (write latency overlaps)
// LDS = 2*16K (K) + 2*16K (V) + 16K (P) = 80 KB -> 2 blocks/CU.
// ---------------------------------------------------------------------------
__global__ __launch_bounds__(256) void flash_attn_v4(const u16* __restrict__ qh,
                                                     const u16* __restrict__ kh,
                                                     const u16* __restrict__ vtg,
                                                     u16* __restrict__ attnb)
{
    // Ks[buf][s][h]: chunk cb = c8 ^ (s&7); addr = s*128 + cb*8 + (h&7)
    __shared__ __align__(16) u16 Ks[2][64 * 128];
    // Vt[buf][h][s]: chunk cb = sb ^ (h&7); addr = h*64 + cb*8 + (s&7)
    __shared__ __align__(16) u16 Vt[2][128 * 64];
    // Ps[m][s]: chunk cb = sb ^ (m&7)
    __shared__ __align__(16) u16 Ps[128 * 64];

    const int yy = blockIdx.y;
    const int qt = (yy < 8) ? (15 - yy) : (yy - 8);   // balanced pairing
    const int bh = blockIdx.x;
    const int b = bh >> 4, n = bh & 15, kvh = n >> 2;
    const int q0 = qt * 128;
    const int tid = threadIdx.x;
    const int wv = tid >> 6, lane = tid & 63;
    const int l15 = lane & 15, quad = lane >> 4;

    const size_t kbase = (size_t)(b * Tdim) * 512 + kvh * 128;
    const size_t vbase = ((size_t)(b * 512 + kvh * 128)) * 2048;
    const int nT = 2 * qt + 2;

    auto stage = [&](int t, int buf) {
        const int s0s = t * 64;
#pragma unroll
        for (int c = 0; c < 4; c++) {
            int j = c * 256 + tid;
            int s = j >> 4;
            int c8 = (j & 15) ^ (s & 7);
            gload16(kh + kbase + (size_t)(s0s + s) * 512 + c8 * 8,
                    &Ks[buf][(c * 256 + wv * 64) * 8]);
            int h = j >> 3;
            int sb = (j & 7) ^ (h & 7);
            gload16(vtg + vbase + (size_t)h * 2048 + s0s + sb * 8,
                    &Vt[buf][(c * 256 + wv * 64) * 8]);
        }
    };

    // issue tile 0 staging first, overlap Q-frag loads with it
    stage(0, 0);

    // ---- Q fragments direct from global (B-operand: n=l15->m, k=quad*8+j->h) ----
    bf16x8 qfrag[2][4];
    {
        const size_t qbase = ((size_t)(b * Tdim + q0 + wv * 32)) * 2048 + n * 128;
#pragma unroll
        for (int mt = 0; mt < 2; mt++)
#pragma unroll
            for (int kt = 0; kt < 4; kt++)
                qfrag[mt][kt] = *(const bf16x8*)(qh + qbase + (size_t)(mt * 16 + l15) * 2048
                                                 + kt * 32 + quad * 8);
    }

    f32x4 Oacc[2][8];
#pragma unroll
    for (int mt = 0; mt < 2; mt++)
#pragma unroll
        for (int ht = 0; ht < 8; ht++) Oacc[mt][ht] = (f32x4){0.f, 0.f, 0.f, 0.f};
    float mrow[2] = {NEG_INF, NEG_INF};
    float lrow[2] = {0.f, 0.f};

    __syncthreads();   // tile 0 staged (vmcnt drained by syncthreads)

    int cur = 0;
    for (int t = 0; t < nT; t++) {
        const int s0 = t * 64;

        // ---- issue next tile's staging into the other buffer (latency hides
        //      under this tile's compute; drained at the end-of-iter barrier) ----
        if (t + 1 < nT) stage(t + 1, cur ^ 1);

        // ---- S^T = K Q^T : tiles nt (s) x mt (m) ----
        f32x4 S[2][4];
#pragma unroll
        for (int mt = 0; mt < 2; mt++)
#pragma unroll
            for (int nt = 0; nt < 4; nt++) S[mt][nt] = (f32x4){0.f, 0.f, 0.f, 0.f};
#pragma unroll
        for (int kt = 0; kt < 4; kt++) {
            bf16x8 kf[4];
#pragma unroll
            for (int nt = 0; nt < 4; nt++) {
                int s = nt * 16 + l15;
                int cb = (kt * 4 + quad) ^ (s & 7);
                kf[nt] = *(const bf16x8*)&Ks[cur][s * 128 + cb * 8];
            }
#pragma unroll
            for (int mt = 0; mt < 2; mt++)
#pragma unroll
                for (int nt = 0; nt < 4; nt++)
                    S[mt][nt] = __builtin_amdgcn_mfma_f32_16x16x32_bf16(kf[nt], qfrag[mt][kt], S[mt][nt], 0, 0, 0);
        }

        // ---- online softmax, exp2 domain, phase-wise over both mt ----
        const bool domask = (t >= nT - 2);
        float sv[2][16];
        float mxv[2];
#pragma unroll
        for (int mt = 0; mt < 2; mt++) {
            const int mg = q0 + wv * 32 + mt * 16 + l15;
#pragma unroll
            for (int nt = 0; nt < 4; nt++)
#pragma unroll
                for (int r = 0; r < 4; r++) {
                    float vv = S[mt][nt][r];          // already scaled (q pre-scale)
                    if (domask) {
                        int sg = s0 + nt * 16 + quad * 4 + r;
                        if (sg > mg) vv = NEG_INF;
                    }
                    sv[mt][nt * 4 + r] = vv;
                }
            mxv[mt] = quad_reduce_max(tree_max16(sv[mt]));
        }
        bool skip[2]; float mNew[2];
#pragma unroll
        for (int mt = 0; mt < 2; mt++) {
            // T13 defer-max: if no row of this wave grew past THR, keep mOld
            skip[mt] = __all(mxv[mt] <= mrow[mt] + DEFER_THR);
            mNew[mt] = skip[mt] ? mrow[mt] : fmaxf(mrow[mt], mxv[mt]);
        }
#pragma unroll
        for (int mt = 0; mt < 2; mt++)
#pragma unroll
            for (int i = 0; i < 16; i++)
                sv[mt][i] = __builtin_amdgcn_exp2f(sv[mt][i] - mNew[mt]);  // masked -> 0
        // ---- early P write: LDS write latency overlaps the sum chain ----
#pragma unroll
        for (int mt = 0; mt < 2; mt++) {
            const int m_l = wv * 32 + mt * 16 + l15;
#pragma unroll
            for (int nt = 0; nt < 4; nt++) {
                int sb = nt * 2 + (quad >> 1);
                int cb = sb ^ (m_l & 7);
                ushort4 pw;
                pw.x = f2bfn(sv[mt][nt * 4 + 0]);
                pw.y = f2bfn(sv[mt][nt * 4 + 1]);
                pw.z = f2bfn(sv[mt][nt * 4 + 2]);
                pw.w = f2bfn(sv[mt][nt * 4 + 3]);
                *(ushort4*)&Ps[m_l * 64 + cb * 8 + (quad & 1) * 4] = pw;
            }
        }
#pragma unroll
        for (int mt = 0; mt < 2; mt++) {
            float ps = quad_reduce_sum(tree_sum16(sv[mt]));
            if (skip[mt]) {
                lrow[mt] += ps;
            } else {
                float alpha = __builtin_amdgcn_exp2f(mrow[mt] - mNew[mt]);
                mrow[mt] = mNew[mt];
                lrow[mt] = lrow[mt] * alpha + ps;
                // rescale O: lane needs alpha of rows quad*4+r (held by lane quad*4+r)
                float a0 = __shfl(alpha, quad * 4 + 0);
                float a1 = __shfl(alpha, quad * 4 + 1);
                float a2 = __shfl(alpha, quad * 4 + 2);
                float a3 = __shfl(alpha, quad * 4 + 3);
#pragma unroll
                for (int ht = 0; ht < 8; ht++) {
                    Oacc[mt][ht][0] *= a0;
                    Oacc[mt][ht][1] *= a1;
                    Oacc[mt][ht][2] *= a2;
                    Oacc[mt][ht][3] *= a3;
                }
            }
        }

        // ---- O += P V ----
#pragma unroll
        for (int k2 = 0; k2 < 2; k2++) {
            bf16x8 pf[2];
#pragma unroll
            for (int mt = 0; mt < 2; mt++) {
                int m_l = wv * 32 + mt * 16 + l15;
                int cb = (k2 * 4 + quad) ^ (m_l & 7);
                pf[mt] = *(const bf16x8*)&Ps[m_l * 64 + cb * 8];
            }
#pragma unroll
            for (int ht = 0; ht < 8; ht++) {
                int h = ht * 16 + l15;
                int cb = (k2 * 4 + quad) ^ (h & 7);
                bf16x8 vf = *(const bf16x8*)&Vt[cur][h * 64 + cb * 8];
#pragma unroll
                for (int mt = 0; mt < 2; mt++)
                    Oacc[mt][ht] = __builtin_amdgcn_mfma_f32_16x16x32_bf16(pf[mt], vf, Oacc[mt][ht], 0, 0, 0);
            }
        }

        __syncthreads();   // drains next-tile vmcnt + all waves done reading buf[cur]
        cur ^= 1;
    }

    // ---- epilogue: l broadcast via shfl (row quad*4+r held by lane quad*4+r) ----
#pragma unroll
    for (int mt = 0; mt < 2; mt++) {
        f32x4 inv;
#pragma unroll
        for (int r = 0; r < 4; r++)
            inv[r] = 1.0f / __shfl(lrow[mt], quad * 4 + r);
        int mg0 = q0 + wv * 32 + mt * 16 + quad * 4;
        u16* dst0 = attnb + ((size_t)(b * Tdim + mg0)) * 2048 + n * 128 + l15;
#pragma unroll
        for (int ht = 0; ht < 8; ht++) {
#pragma unroll
            for (int r = 0; r < 4; r++)
                dst0[(size_t)r * 2048 + ht * 16] = f2bfn(Oacc[mt][ht][r] * inv[r]);
        }
    }
}

extern "C" void kernel_launch(void* const* d_in, const int* in_sizes, int n_in,
                              void* d_out, int out_size, void* d_ws, size_t ws_size,
                              hipStream_t stream) {
    const float* Xq    = (const float*)d_in[0];
    const float* Xkv   = (const float*)d_in[1];
    const int*   qpos  = (const int*)d_in[2];
    const int*   kvpos = (const int*)d_in[3];
    const float* Wq    = (const float*)d_in[4];
    const float* Wk    = (const float*)d_in[5];
    const float* Wv    = (const float*)d_in[6];
    const float* Wo    = (const float*)d_in[7];
    float* out = (float*)d_out;

    char* w = (char*)d_ws;
    u16* xq_bf = (u16*)(w);                    // 16 MB
    u16* xkv_bf= (u16*)(w + (16u << 20));      // 16 MB
    u16* qraw  = (u16*)(w + (32u << 20));      // 16 MB (roped in place)
    u16* kraw  = (u16*)(w + (48u << 20));      //  4 MB (roped in place)
    u16* vt    = (u16*)(w + (52u << 20));      //  4 MB [(b*4+kvh)*128+h][2048]
    u16* wq_t  = (u16*)(w + (56u << 20));      //  8 MB
    u16* wk_t  = (u16*)(w + (64u << 20));      //  2 MB
    u16* wv_t  = (u16*)(w + (66u << 20));      //  2 MB
    u16* wo_t  = (u16*)(w + (68u << 20));      //  8 MB
    u16* attnb = (u16*)(w);                    // aliases xq_bf (dead by then)

    cvt_x<<<8192, 256, 0, stream>>>(Xq, Xkv, xq_bf, xkv_bf);
    cvt_w_t<<<dim3(32, 32), 256, 0, stream>>>(Wq, wq_t, 2048, 2048);
    cvt_w_t<<<dim3(8, 32),  256, 0, stream>>>(Wk, wk_t, 2048, 512);
    cvt_w_t<<<dim3(8, 32),  256, 0, stream>>>(Wv, wv_t, 2048, 512);
    cvt_w_t<<<dim3(32, 32), 256, 0, stream>>>(Wo, wo_t, 2048, 2048);
    qkv_gemm_bf<<<dim3(24, 32), 256, 0, stream>>>(xq_bf, xkv_bf, wq_t, wk_t, wv_t,
                                                  qraw, kraw, vt);
    rope_bf<<<5120, 256, 0, stream>>>(qraw, kraw, qpos, kvpos);
    flash_attn_v4<<<dim3(32, 16), 256, 0, stream>>>(qraw, kraw, vt, attnb);
    oproj_gemm_bf<<<dim3(16, 32), 256, 0, stream>>>(attnb, wo_t, out);
}

// Round 3
// 377.515 us; speedup vs baseline: 1.0890x; 1.0713x over previous
//
#include <hip/hip_runtime.h>
#include <hip/hip_bf16.h>
#include <cstdint>
#include <cstddef>

#define Bdim 2
#define Tdim 2048
#define Ddim 2048
#define NHq  16
#define NKV  4
#define HD   128
#define SCALE 0.08838834764831845f
// SCALE * log2(e): folded into q inside rope_bf so attention works in exp2 domain
#define QPRESCALE (0.08838834764831845f * 1.4426950408889634f)
#define NEG_INF (-3.0e38f)
// defer-max threshold (log2 domain): e-domain 8 -> 8*log2e ~ 11.5
#define DEFER_THR 11.5f

typedef unsigned short u16;
typedef unsigned int   u32;
typedef __bf16 bf16x8 __attribute__((ext_vector_type(8)));
typedef float  f32x4  __attribute__((ext_vector_type(4)));

__device__ __forceinline__ u16 f2bf(float f) {
    unsigned int u = __float_as_uint(f);
    u += 0x7FFFu + ((u >> 16) & 1u);   // RNE
    return (u16)(u >> 16);
}
// native cast — compiler emits (packed) v_cvt_*_bf16_f32, RNE
__device__ __forceinline__ u16 f2bfn(float f) {
    __bf16 h = (__bf16)f;
    return __builtin_bit_cast(u16, h);
}
__device__ __forceinline__ float bf2f(u16 s) {
    return __uint_as_float(((unsigned int)s) << 16);
}

// ---------------------------------------------------------------------------
// cross-quad (xor16 / xor32) wave reductions via permlane swaps (VALU-speed).
// ---------------------------------------------------------------------------
#if __has_builtin(__builtin_amdgcn_permlane16_swap) && __has_builtin(__builtin_amdgcn_permlane32_swap)
#define HAVE_PERMLANE_SWAP 1
#endif

__device__ __forceinline__ float quad_reduce_max(float v) {
#ifdef HAVE_PERMLANE_SWAP
    auto r = __builtin_amdgcn_permlane16_swap(__float_as_uint(v), __float_as_uint(v), false, false);
    float m = fmaxf(__uint_as_float(r[0]), __uint_as_float(r[1]));
    auto r2 = __builtin_amdgcn_permlane32_swap(__float_as_uint(m), __float_as_uint(m), false, false);
    return fmaxf(__uint_as_float(r2[0]), __uint_as_float(r2[1]));
#else
    v = fmaxf(v, __shfl_xor(v, 16));
    return fmaxf(v, __shfl_xor(v, 32));
#endif
}
__device__ __forceinline__ float quad_reduce_sum(float v) {
#ifdef HAVE_PERMLANE_SWAP
    auto r = __builtin_amdgcn_permlane16_swap(__float_as_uint(v), __float_as_uint(v), false, false);
    float s = __uint_as_float(r[0]) + __uint_as_float(r[1]);
    auto r2 = __builtin_amdgcn_permlane32_swap(__float_as_uint(s), __float_as_uint(s), false, false);
    return __uint_as_float(r2[0]) + __uint_as_float(r2[1]);
#else
    v += __shfl_xor(v, 16);
    return v + __shfl_xor(v, 32);
#endif
}

// depth-4 trees (compiler won't reassociate FP chains without fast-math)
__device__ __forceinline__ float tree_max16(const float (&s)[16]) {
    float a0 = fmaxf(s[0], s[1]),  a1 = fmaxf(s[2], s[3]);
    float a2 = fmaxf(s[4], s[5]),  a3 = fmaxf(s[6], s[7]);
    float a4 = fmaxf(s[8], s[9]),  a5 = fmaxf(s[10], s[11]);
    float a6 = fmaxf(s[12], s[13]), a7 = fmaxf(s[14], s[15]);
    float b0 = fmaxf(a0, a1), b1 = fmaxf(a2, a3);
    float b2 = fmaxf(a4, a5), b3 = fmaxf(a6, a7);
    return fmaxf(fmaxf(b0, b1), fmaxf(b2, b3));
}
__device__ __forceinline__ float tree_sum16(const float (&s)[16]) {
    float a0 = s[0] + s[1],  a1 = s[2] + s[3];
    float a2 = s[4] + s[5],  a3 = s[6] + s[7];
    float a4 = s[8] + s[9],  a5 = s[10] + s[11];
    float a6 = s[12] + s[13], a7 = s[14] + s[15];
    float b0 = a0 + a1, b1 = a2 + a3, b2 = a4 + a5, b3 = a6 + a7;
    return (b0 + b1) + (b2 + b3);
}

// async global->LDS, 16B per lane. LDS dest is wave-uniform base + lane*16.
typedef __attribute__((address_space(1))) const u32 gbl_u32;
typedef __attribute__((address_space(3))) u32 lds_u32;
__device__ __forceinline__ void gload16(const void* g, void* l) {
    __builtin_amdgcn_global_load_lds((gbl_u32*)(uintptr_t)g, (lds_u32*)(uintptr_t)l, 16, 0, 0);
}

// ---------------------------------------------------------------------------
// fp32 -> bf16 straight convert for Xq, Xkv. 8 elems/thread.
// ---------------------------------------------------------------------------
__global__ __launch_bounds__(256) void cvt_x(const float* __restrict__ Xq,
                                             const float* __restrict__ Xkv,
                                             u16* __restrict__ oq,
                                             u16* __restrict__ okv)
{
    const size_t NE = (size_t)4096 * 2048 / 8;
    size_t idx = (size_t)blockIdx.x * 256 + threadIdx.x;
    const float* src; u16* dst; size_t off;
    if (idx < NE) { src = Xq;  dst = oq;  off = idx * 8; }
    else          { src = Xkv; dst = okv; off = (idx - NE) * 8; }
    float4 a = *(const float4*)&src[off];
    float4 b = *(const float4*)&src[off + 4];
    ushort4 r0, r1;
    r0.x = f2bf(a.x); r0.y = f2bf(a.y); r0.z = f2bf(a.z); r0.w = f2bf(a.w);
    r1.x = f2bf(b.x); r1.y = f2bf(b.y); r1.z = f2bf(b.z); r1.w = f2bf(b.w);
    *(ushort4*)&dst[off] = r0;
    *(ushort4*)&dst[off + 4] = r1;
}

// ---------------------------------------------------------------------------
// fp32 W[R][C] -> bf16 W^T[C][R], 64x64 LDS tiles. grid (C/64, R/64).
// ---------------------------------------------------------------------------
__global__ __launch_bounds__(256) void cvt_w_t(const float* __restrict__ src,
                                               u16* __restrict__ dst, int R, int C)
{
    __shared__ u16 t[64][72];
    const int r0 = blockIdx.y * 64, c0 = blockIdx.x * 64;
    const int tid = threadIdx.x;
    const int tr = tid >> 4, tc4 = (tid & 15) * 4;
#pragma unroll
    for (int p = 0; p < 4; p++) {
        int r = p * 16 + tr;
        float4 v = *(const float4*)&src[(size_t)(r0 + r) * C + c0 + tc4];
        t[tc4 + 0][r] = f2bf(v.x);
        t[tc4 + 1][r] = f2bf(v.y);
        t[tc4 + 2][r] = f2bf(v.z);
        t[tc4 + 3][r] = f2bf(v.w);
    }
    __syncthreads();
#pragma unroll
    for (int p = 0; p < 4; p++) {
        int cc = p * 16 + tr;
        ushort4 w = *(const ushort4*)&t[cc][tc4];
        *(ushort4*)&dst[(size_t)(c0 + cc) * R + r0 + tc4] = w;
    }
}

// ---------------------------------------------------------------------------
// bf16 MFMA GEMM mainloop (m97 structure)
// ---------------------------------------------------------------------------
__device__ __forceinline__ void bf16_gemm_mainloop(const u16* __restrict__ A,
                                                   const u16* __restrict__ Bt,
                                                   int m0, int n0,
                                                   u16 (&As)[128 * 32],
                                                   u16 (&Bs)[128 * 32],
                                                   f32x4 (&acc)[4][4])
{
    const int tid = threadIdx.x;
    const int wv = tid >> 6, lane = tid & 63;
    const int l15 = lane & 15, quad = lane >> 4;
    const int wr = wv >> 1, wc = wv & 1;

#pragma unroll
    for (int mt = 0; mt < 4; mt++)
#pragma unroll
        for (int nt = 0; nt < 4; nt++) acc[mt][nt] = (f32x4){0.f, 0.f, 0.f, 0.f};

    for (int k0 = 0; k0 < 2048; k0 += 32) {
        __syncthreads();
#pragma unroll
        for (int j = 0; j < 2; j++) {
            int c = wv * 128 + j * 64 + lane;
            const u16* ga = A + (size_t)(m0 + (c >> 2)) * 2048 + k0 + (c & 3) * 8;
            gload16(ga, &As[(wv * 128 + j * 64) * 8]);
            const u16* gb = Bt + (size_t)(n0 + (c >> 2)) * 2048 + k0 + (c & 3) * 8;
            gload16(gb, &Bs[(wv * 128 + j * 64) * 8]);
        }
        __syncthreads();

        bf16x8 af[4], bfr[4];
#pragma unroll
        for (int mt = 0; mt < 4; mt++)
            af[mt] = *(const bf16x8*)&As[(wr * 64 + mt * 16 + l15) * 32 + quad * 8];
#pragma unroll
        for (int nt = 0; nt < 4; nt++)
            bfr[nt] = *(const bf16x8*)&Bs[(wc * 64 + nt * 16 + l15) * 32 + quad * 8];
#pragma unroll
        for (int mt = 0; mt < 4; mt++)
#pragma unroll
            for (int nt = 0; nt < 4; nt++)
                acc[mt][nt] = __builtin_amdgcn_mfma_f32_16x16x32_bf16(af[mt], bfr[nt], acc[mt][nt], 0, 0, 0);
    }
}

// Fused QKV: grid (24, 32).
__global__ __launch_bounds__(256) void qkv_gemm_bf(const u16* __restrict__ Xq,
                                                   const u16* __restrict__ Xkv,
                                                   const u16* __restrict__ Wqt,
                                                   const u16* __restrict__ Wkt,
                                                   const u16* __restrict__ Wvt,
                                                   u16* __restrict__ qraw,
                                                   u16* __restrict__ kraw,
                                                   u16* __restrict__ vt)
{
    __shared__ __align__(16) u16 As[128 * 32];
    __shared__ __align__(16) u16 Bs[128 * 32];
    f32x4 acc[4][4];
    const int bx = blockIdx.x, m0 = blockIdx.y * 128;
    const u16 *A, *Bt; int n0;
    if (bx < 16)      { A = Xq;  Bt = Wqt; n0 = bx * 128; }
    else if (bx < 20) { A = Xkv; Bt = Wkt; n0 = (bx - 16) * 128; }
    else              { A = Xkv; Bt = Wvt; n0 = (bx - 20) * 128; }
    bf16_gemm_mainloop(A, Bt, m0, n0, As, Bs, acc);

    const int tid = threadIdx.x;
    const int wv = tid >> 6, lane = tid & 63;
    const int l15 = lane & 15, quad = lane >> 4;
    const int wr = wv >> 1, wc = wv & 1;

    if (bx < 20) {
        u16* out; int ldw;
        if (bx < 16) { out = qraw; ldw = 2048; }
        else         { out = kraw; ldw = 512; }
#pragma unroll
        for (int mt = 0; mt < 4; mt++)
#pragma unroll
            for (int nt = 0; nt < 4; nt++) {
                int col = n0 + wc * 64 + nt * 16 + l15;
                int r = m0 + wr * 64 + mt * 16 + quad * 4;
#pragma unroll
                for (int reg = 0; reg < 4; reg++)
                    out[(size_t)(r + reg) * ldw + col] = f2bf(acc[mt][nt][reg]);
            }
    } else {
        const int b = m0 >> 11, tb = m0 & 2047;
#pragma unroll
        for (int mt = 0; mt < 4; mt++)
#pragma unroll
            for (int nt = 0; nt < 4; nt++) {
                int col = n0 + wc * 64 + nt * 16 + l15;
                int tloc = tb + wr * 64 + mt * 16 + quad * 4;
                ushort4 w4;
                w4.x = f2bf(acc[mt][nt][0]);
                w4.y = f2bf(acc[mt][nt][1]);
                w4.z = f2bf(acc[mt][nt][2]);
                w4.w = f2bf(acc[mt][nt][3]);
                *(ushort4*)&vt[((size_t)b * 512 + col) * 2048 + tloc] = w4;
            }
    }
}

// Output projection: grid (16, 32).
__global__ __launch_bounds__(256) void oproj_gemm_bf(const u16* __restrict__ attnb,
                                                     const u16* __restrict__ Wot,
                                                     float* __restrict__ out)
{
    __shared__ __align__(16) u16 As[128 * 32];
    __shared__ __align__(16) u16 Bs[128 * 32];
    f32x4 acc[4][4];
    const int m0 = blockIdx.y * 128, n0 = blockIdx.x * 128;
    bf16_gemm_mainloop(attnb, Wot, m0, n0, As, Bs, acc);
    const int tid = threadIdx.x;
    const int wv = tid >> 6, lane = tid & 63;
    const int l15 = lane & 15, quad = lane >> 4;
    const int wr = wv >> 1, wc = wv & 1;
#pragma unroll
    for (int mt = 0; mt < 4; mt++)
#pragma unroll
        for (int nt = 0; nt < 4; nt++) {
            int col = n0 + wc * 64 + nt * 16 + l15;
            int r = m0 + wr * 64 + mt * 16 + quad * 4;
#pragma unroll
            for (int reg = 0; reg < 4; reg++)
                out[(size_t)(r + reg) * 2048 + col] = acc[mt][nt][reg];
        }
}

// In-place RoPE on bf16 q/k. q additionally pre-scaled by SCALE*log2e so
// flash attention's softmax runs in the exp2 domain with no per-score mult.
__global__ __launch_bounds__(256) void rope_bf(u16* __restrict__ q,
                                               u16* __restrict__ k,
                                               const int* __restrict__ qpos,
                                               const int* __restrict__ kvpos)
{
    const int qTh = Bdim * Tdim * NHq * 16;
    int idx = blockIdx.x * 256 + threadIdx.x;
    u16* base; int h4; int pos; float osc;
    if (idx < qTh) {
        int rn = idx >> 4; h4 = (idx & 15) * 4;
        pos = qpos[rn >> 4];
        base = q + (size_t)rn * HD;
        osc = QPRESCALE;
    } else {
        int j = idx - qTh;
        int rn = j >> 4; h4 = (j & 15) * 4;
        pos = kvpos[rn >> 2];
        base = k + (size_t)rn * HD;
        osc = 1.0f;
    }
    ushort4 a = *(const ushort4*)&base[h4];
    ushort4 bvec = *(const ushort4*)&base[h4 + 64];
    u16 av[4] = {a.x, a.y, a.z, a.w};
    u16 bv[4] = {bvec.x, bvec.y, bvec.z, bvec.w};
#pragma unroll
    for (int j = 0; j < 4; j++) {
        float inv_ts = expf(-(float)(h4 + j) * 0.14391156831f);
        float ang = (float)pos * inv_ts;
        float s, c;
        sincosf(ang, &s, &c);
        s *= osc; c *= osc;
        float x1 = bf2f(av[j]), x2 = bf2f(bv[j]);
        av[j] = f2bf(x1 * c - x2 * s);
        bv[j] = f2bf(x2 * c + x1 * s);
    }
    ushort4 ra, rb;
    ra.x = av[0]; ra.y = av[1]; ra.z = av[2]; ra.w = av[3];
    rb.x = bv[0]; rb.y = bv[1]; rb.z = bv[2]; rb.w = bv[3];
    *(ushort4*)&base[h4] = ra;
    *(ushort4*)&base[h4 + 64] = rb;
}

// ---------------------------------------------------------------------------
// Flash attention v5: BQ=128 split over EIGHT waves (16 rows each), BKV=64.
// 512-thread blocks; LDS unchanged at 80 KB -> still 2 blocks/CU, but now
// 16 waves/CU = 4 waves/SIMD (was 2): 2x the wave interleave to hide the
// per-iteration dependence chain. Per-wave state halves (fits 128 VGPR for
// 4 waves/SIMD, enforced via __launch_bounds__(512, 4)).
// All LDS layouts/swizzles/staging identical to v4.
// ---------------------------------------------------------------------------
__global__ __launch_bounds__(512, 4) void flash_attn_v5(const u16* __restrict__ qh,
                                                        const u16* __restrict__ kh,
                                                        const u16* __restrict__ vtg,
                                                        u16* __restrict__ attnb)
{
    // Ks[buf][s][h]: chunk cb = c8 ^ (s&7); addr = s*128 + cb*8 + (h&7)
    __shared__ __align__(16) u16 Ks[2][64 * 128];
    // Vt[buf][h][s]: chunk cb = sb ^ (h&7); addr = h*64 + cb*8 + (s&7)
    __shared__ __align__(16) u16 Vt[2][128 * 64];
    // Ps[m][s]: chunk cb = sb ^ (m&7)
    __shared__ __align__(16) u16 Ps[128 * 64];

    const int yy = blockIdx.y;
    const int qt = (yy < 8) ? (15 - yy) : (yy - 8);   // balanced pairing
    const int bh = blockIdx.x;
    const int b = bh >> 4, n = bh & 15, kvh = n >> 2;
    const int q0 = qt * 128;
    const int tid = threadIdx.x;
    const int wv = tid >> 6, lane = tid & 63;          // wv in 0..7
    const int l15 = lane & 15, quad = lane >> 4;

    const size_t kbase = (size_t)(b * Tdim) * 512 + kvh * 128;
    const size_t vbase = ((size_t)(b * 512 + kvh * 128)) * 2048;
    const int nT = 2 * qt + 2;

    auto stage = [&](int t, int buf) {
        const int s0s = t * 64;
#pragma unroll
        for (int c = 0; c < 2; c++) {
            int j = c * 512 + tid;        // 0..1023
            int s = j >> 4;               // 0..63
            int c8 = (j & 15) ^ (s & 7);
            gload16(kh + kbase + (size_t)(s0s + s) * 512 + c8 * 8,
                    &Ks[buf][(c * 512 + wv * 64) * 8]);
            int h = j >> 3;               // 0..127
            int sb = (j & 7) ^ (h & 7);
            gload16(vtg + vbase + (size_t)h * 2048 + s0s + sb * 8,
                    &Vt[buf][(c * 512 + wv * 64) * 8]);
        }
    };

    // issue tile 0 staging first, overlap Q-frag loads with it
    stage(0, 0);

    // ---- Q fragments direct from global (B-operand: n=l15->m, k=quad*8+j->h) ----
    // wave owns 16 q rows: m_l = wv*16 + l15
    bf16x8 qfrag[4];
    {
        const size_t qbase = ((size_t)(b * Tdim + q0 + wv * 16)) * 2048 + n * 128;
#pragma unroll
        for (int kt = 0; kt < 4; kt++)
            qfrag[kt] = *(const bf16x8*)(qh + qbase + (size_t)l15 * 2048
                                          + kt * 32 + quad * 8);
    }

    f32x4 Oacc[8];
#pragma unroll
    for (int ht = 0; ht < 8; ht++) Oacc[ht] = (f32x4){0.f, 0.f, 0.f, 0.f};
    float mrow = NEG_INF;
    float lrow = 0.f;

    __syncthreads();   // tile 0 staged (vmcnt drained by syncthreads)

    int cur = 0;
    for (int t = 0; t < nT; t++) {
        const int s0 = t * 64;

        // ---- issue next tile's staging into the other buffer (latency hides
        //      under this tile's compute; drained at the end-of-iter barrier) ----
        if (t + 1 < nT) stage(t + 1, cur ^ 1);

        // ---- S^T = K Q^T : tiles nt (s) ----
        f32x4 S[4];
#pragma unroll
        for (int nt = 0; nt < 4; nt++) S[nt] = (f32x4){0.f, 0.f, 0.f, 0.f};
#pragma unroll
        for (int kt = 0; kt < 4; kt++) {
            bf16x8 kf[4];
#pragma unroll
            for (int nt = 0; nt < 4; nt++) {
                int s = nt * 16 + l15;
                int cb = (kt * 4 + quad) ^ (s & 7);
                kf[nt] = *(const bf16x8*)&Ks[cur][s * 128 + cb * 8];
            }
#pragma unroll
            for (int nt = 0; nt < 4; nt++)
                S[nt] = __builtin_amdgcn_mfma_f32_16x16x32_bf16(kf[nt], qfrag[kt], S[nt], 0, 0, 0);
        }

        // ---- online softmax, exp2 domain ----
        const bool domask = (t >= nT - 2);
        const int m_l = wv * 16 + l15;
        const int mg = q0 + m_l;
        float sv[16];
#pragma unroll
        for (int nt = 0; nt < 4; nt++)
#pragma unroll
            for (int r = 0; r < 4; r++) {
                float vv = S[nt][r];              // already scaled (q pre-scale)
                if (domask) {
                    int sg = s0 + nt * 16 + quad * 4 + r;
                    if (sg > mg) vv = NEG_INF;
                }
                sv[nt * 4 + r] = vv;
            }
        float mx = quad_reduce_max(tree_max16(sv));
        // T13 defer-max: if no row of this wave grew past THR, keep mOld
        const bool skip = __all(mx <= mrow + DEFER_THR);
        const float mNew = skip ? mrow : fmaxf(mrow, mx);
#pragma unroll
        for (int i = 0; i < 16; i++)
            sv[i] = __builtin_amdgcn_exp2f(sv[i] - mNew);   // masked -> 0
        // ---- early P write: LDS write latency overlaps the sum chain ----
#pragma unroll
        for (int nt = 0; nt < 4; nt++) {
            int sb = nt * 2 + (quad >> 1);
            int cb = sb ^ (m_l & 7);
            ushort4 pw;
            pw.x = f2bfn(sv[nt * 4 + 0]);
            pw.y = f2bfn(sv[nt * 4 + 1]);
            pw.z = f2bfn(sv[nt * 4 + 2]);
            pw.w = f2bfn(sv[nt * 4 + 3]);
            *(ushort4*)&Ps[m_l * 64 + cb * 8 + (quad & 1) * 4] = pw;
        }
        {
            float ps = quad_reduce_sum(tree_sum16(sv));
            if (skip) {
                lrow += ps;
            } else {
                float alpha = __builtin_amdgcn_exp2f(mrow - mNew);
                mrow = mNew;
                lrow = lrow * alpha + ps;
                // rescale O: lane needs alpha of rows quad*4+r (held by lane quad*4+r)
                float a0 = __shfl(alpha, quad * 4 + 0);
                float a1 = __shfl(alpha, quad * 4 + 1);
                float a2 = __shfl(alpha, quad * 4 + 2);
                float a3 = __shfl(alpha, quad * 4 + 3);
#pragma unroll
                for (int ht = 0; ht < 8; ht++) {
                    Oacc[ht][0] *= a0;
                    Oacc[ht][1] *= a1;
                    Oacc[ht][2] *= a2;
                    Oacc[ht][3] *= a3;
                }
            }
        }

        // ---- O += P V ----
#pragma unroll
        for (int k2 = 0; k2 < 2; k2++) {
            int cbp = (k2 * 4 + quad) ^ (m_l & 7);
            bf16x8 pf = *(const bf16x8*)&Ps[m_l * 64 + cbp * 8];
#pragma unroll
            for (int ht = 0; ht < 8; ht++) {
                int h = ht * 16 + l15;
                int cb = (k2 * 4 + quad) ^ (h & 7);
                bf16x8 vf = *(const bf16x8*)&Vt[cur][h * 64 + cb * 8];
                Oacc[ht] = __builtin_amdgcn_mfma_f32_16x16x32_bf16(pf, vf, Oacc[ht], 0, 0, 0);
            }
        }

        __syncthreads();   // drains next-tile vmcnt + all waves done reading buf[cur]
        cur ^= 1;
    }

    // ---- epilogue: l broadcast via shfl (row quad*4+r held by lane quad*4+r) ----
    {
        f32x4 inv;
#pragma unroll
        for (int r = 0; r < 4; r++)
            inv[r] = 1.0f / __shfl(lrow, quad * 4 + r);
        int mg0 = q0 + wv * 16 + quad * 4;
        u16* dst0 = attnb + ((size_t)(b * Tdim + mg0)) * 2048 + n * 128 + l15;
#pragma unroll
        for (int ht = 0; ht < 8; ht++) {
#pragma unroll
            for (int r = 0; r < 4; r++)
                dst0[(size_t)r * 2048 + ht * 16] = f2bfn(Oacc[ht][r] * inv[r]);
        }
    }
}

extern "C" void kernel_launch(void* const* d_in, const int* in_sizes, int n_in,
                              void* d_out, int out_size, void* d_ws, size_t ws_size,
                              hipStream_t stream) {
    const float* Xq    = (const float*)d_in[0];
    const float* Xkv   = (const float*)d_in[1];
    const int*   qpos  = (const int*)d_in[2];
    const int*   kvpos = (const int*)d_in[3];
    const float* Wq    = (const float*)d_in[4];
    const float* Wk    = (const float*)d_in[5];
    const float* Wv    = (const float*)d_in[6];
    const float* Wo    = (const float*)d_in[7];
    float* out = (float*)d_out;

    char* w = (char*)d_ws;
    u16* xq_bf = (u16*)(w);                    // 16 MB
    u16* xkv_bf= (u16*)(w + (16u << 20));      // 16 MB
    u16* qraw  = (u16*)(w + (32u << 20));      // 16 MB (roped in place)
    u16* kraw  = (u16*)(w + (48u << 20));      //  4 MB (roped in place)
    u16* vt    = (u16*)(w + (52u << 20));      //  4 MB [(b*4+kvh)*128+h][2048]
    u16* wq_t  = (u16*)(w + (56u << 20));      //  8 MB
    u16* wk_t  = (u16*)(w + (64u << 20));      //  2 MB
    u16* wv_t  = (u16*)(w + (66u << 20));      //  2 MB
    u16* wo_t  = (u16*)(w + (68u << 20));      //  8 MB
    u16* attnb = (u16*)(w);                    // aliases xq_bf (dead by then)

    cvt_x<<<8192, 256, 0, stream>>>(Xq, Xkv, xq_bf, xkv_bf);
    cvt_w_t<<<dim3(32, 32), 256, 0, stream>>>(Wq, wq_t, 2048, 2048);
    cvt_w_t<<<dim3(8, 32),  256, 0, stream>>>(Wk, wk_t, 2048, 512);
    cvt_w_t<<<dim3(8, 32),  256, 0, stream>>>(Wv, wv_t, 2048, 512);
    cvt_w_t<<<dim3(32, 32), 256, 0, stream>>>(Wo, wo_t, 2048, 2048);
    qkv_gemm_bf<<<dim3(24, 32), 256, 0, stream>>>(xq_bf, xkv_bf, wq_t, wk_t, wv_t,
                                                  qraw, kraw, vt);
    rope_bf<<<5120, 256, 0, stream>>>(qraw, kraw, qpos, kvpos);
    flash_attn_v5<<<dim3(32, 16), 512, 0, stream>>>(qraw, kraw, vt, attnb);
    oproj_gemm_bf<<<dim3(16, 32), 256, 0, stream>>>(attnb, wo_t, out);
}

// Round 4
// 353.656 us; speedup vs baseline: 1.1625x; 1.0675x over previous
//
#include <hip/hip_runtime.h>
#include <hip/hip_bf16.h>
#include <cstdint>
#include <cstddef>

#define Bdim 2
#define Tdim 2048
#define Ddim 2048
#define NHq  16
#define NKV  4
#define HD   128
#define SCALE 0.08838834764831845f
// SCALE * log2(e): folded into q inside rope_bf so attention works in exp2 domain
#define QPRESCALE (0.08838834764831845f * 1.4426950408889634f)
#define NEG_INF (-3.0e38f)
// defer-max threshold (log2 domain): e-domain 8 -> 8*log2e ~ 11.5
#define DEFER_THR 11.5f

typedef unsigned short u16;
typedef unsigned int   u32;
typedef __bf16 bf16x8 __attribute__((ext_vector_type(8)));
typedef float  f32x4  __attribute__((ext_vector_type(4)));

__device__ __forceinline__ u16 f2bf(float f) {
    unsigned int u = __float_as_uint(f);
    u += 0x7FFFu + ((u >> 16) & 1u);   // RNE
    return (u16)(u >> 16);
}
// native cast — compiler emits (packed) v_cvt_*_bf16_f32, RNE
__device__ __forceinline__ u16 f2bfn(float f) {
    __bf16 h = (__bf16)f;
    return __builtin_bit_cast(u16, h);
}
__device__ __forceinline__ float bf2f(u16 s) {
    return __uint_as_float(((unsigned int)s) << 16);
}

// ---------------------------------------------------------------------------
// cross-quad (xor16 / xor32) wave reductions via permlane swaps (VALU-speed).
// ---------------------------------------------------------------------------
#if __has_builtin(__builtin_amdgcn_permlane16_swap) && __has_builtin(__builtin_amdgcn_permlane32_swap)
#define HAVE_PERMLANE_SWAP 1
#endif

__device__ __forceinline__ float quad_reduce_max(float v) {
#ifdef HAVE_PERMLANE_SWAP
    auto r = __builtin_amdgcn_permlane16_swap(__float_as_uint(v), __float_as_uint(v), false, false);
    float m = fmaxf(__uint_as_float(r[0]), __uint_as_float(r[1]));
    auto r2 = __builtin_amdgcn_permlane32_swap(__float_as_uint(m), __float_as_uint(m), false, false);
    return fmaxf(__uint_as_float(r2[0]), __uint_as_float(r2[1]));
#else
    v = fmaxf(v, __shfl_xor(v, 16));
    return fmaxf(v, __shfl_xor(v, 32));
#endif
}
__device__ __forceinline__ float quad_reduce_sum(float v) {
#ifdef HAVE_PERMLANE_SWAP
    auto r = __builtin_amdgcn_permlane16_swap(__float_as_uint(v), __float_as_uint(v), false, false);
    float s = __uint_as_float(r[0]) + __uint_as_float(r[1]);
    auto r2 = __builtin_amdgcn_permlane32_swap(__float_as_uint(s), __float_as_uint(s), false, false);
    return __uint_as_float(r2[0]) + __uint_as_float(r2[1]);
#else
    v += __shfl_xor(v, 16);
    return v + __shfl_xor(v, 32);
#endif
}

// depth-4 trees (compiler won't reassociate FP chains without fast-math)
__device__ __forceinline__ float tree_max16(const float (&s)[16]) {
    float a0 = fmaxf(s[0], s[1]),  a1 = fmaxf(s[2], s[3]);
    float a2 = fmaxf(s[4], s[5]),  a3 = fmaxf(s[6], s[7]);
    float a4 = fmaxf(s[8], s[9]),  a5 = fmaxf(s[10], s[11]);
    float a6 = fmaxf(s[12], s[13]), a7 = fmaxf(s[14], s[15]);
    float b0 = fmaxf(a0, a1), b1 = fmaxf(a2, a3);
    float b2 = fmaxf(a4, a5), b3 = fmaxf(a6, a7);
    return fmaxf(fmaxf(b0, b1), fmaxf(b2, b3));
}
__device__ __forceinline__ float tree_sum16(const float (&s)[16]) {
    float a0 = s[0] + s[1],  a1 = s[2] + s[3];
    float a2 = s[4] + s[5],  a3 = s[6] + s[7];
    float a4 = s[8] + s[9],  a5 = s[10] + s[11];
    float a6 = s[12] + s[13], a7 = s[14] + s[15];
    float b0 = a0 + a1, b1 = a2 + a3, b2 = a4 + a5, b3 = a6 + a7;
    return (b0 + b1) + (b2 + b3);
}

// async global->LDS, 16B per lane. LDS dest is wave-uniform base + lane*16.
typedef __attribute__((address_space(1))) const u32 gbl_u32;
typedef __attribute__((address_space(3))) u32 lds_u32;
__device__ __forceinline__ void gload16(const void* g, void* l) {
    __builtin_amdgcn_global_load_lds((gbl_u32*)(uintptr_t)g, (lds_u32*)(uintptr_t)l, 16, 0, 0);
}

// ---------------------------------------------------------------------------
// fp32 -> bf16 straight convert for Xq, Xkv. 8 elems/thread.
// ---------------------------------------------------------------------------
__global__ __launch_bounds__(256) void cvt_x(const float* __restrict__ Xq,
                                             const float* __restrict__ Xkv,
                                             u16* __restrict__ oq,
                                             u16* __restrict__ okv)
{
    const size_t NE = (size_t)4096 * 2048 / 8;
    size_t idx = (size_t)blockIdx.x * 256 + threadIdx.x;
    const float* src; u16* dst; size_t off;
    if (idx < NE) { src = Xq;  dst = oq;  off = idx * 8; }
    else          { src = Xkv; dst = okv; off = (idx - NE) * 8; }
    float4 a = *(const float4*)&src[off];
    float4 b = *(const float4*)&src[off + 4];
    ushort4 r0, r1;
    r0.x = f2bf(a.x); r0.y = f2bf(a.y); r0.z = f2bf(a.z); r0.w = f2bf(a.w);
    r1.x = f2bf(b.x); r1.y = f2bf(b.y); r1.z = f2bf(b.z); r1.w = f2bf(b.w);
    *(ushort4*)&dst[off] = r0;
    *(ushort4*)&dst[off + 4] = r1;
}

// ---------------------------------------------------------------------------
// fp32 W[R][C] -> bf16 W^T[C][R], 64x64 LDS tiles. grid (C/64, R/64).
// ---------------------------------------------------------------------------
__global__ __launch_bounds__(256) void cvt_w_t(const float* __restrict__ src,
                                               u16* __restrict__ dst, int R, int C)
{
    __shared__ u16 t[64][72];
    const int r0 = blockIdx.y * 64, c0 = blockIdx.x * 64;
    const int tid = threadIdx.x;
    const int tr = tid >> 4, tc4 = (tid & 15) * 4;
#pragma unroll
    for (int p = 0; p < 4; p++) {
        int r = p * 16 + tr;
        float4 v = *(const float4*)&src[(size_t)(r0 + r) * C + c0 + tc4];
        t[tc4 + 0][r] = f2bf(v.x);
        t[tc4 + 1][r] = f2bf(v.y);
        t[tc4 + 2][r] = f2bf(v.z);
        t[tc4 + 3][r] = f2bf(v.w);
    }
    __syncthreads();
#pragma unroll
    for (int p = 0; p < 4; p++) {
        int cc = p * 16 + tr;
        ushort4 w = *(const ushort4*)&t[cc][tc4];
        *(ushort4*)&dst[(size_t)(c0 + cc) * R + r0 + tc4] = w;
    }
}

// ---------------------------------------------------------------------------
// bf16 MFMA GEMM mainloop, double-buffered 2-phase (T3-minimum):
// issue next K-tile's global_load_lds into buf^1, compute buf, ONE barrier
// per K-step (drains vmcnt for the prefetch + LDS reads of cur).
// ---------------------------------------------------------------------------
__device__ __forceinline__ void bf16_gemm_mainloop(const u16* __restrict__ A,
                                                   const u16* __restrict__ Bt,
                                                   int m0, int n0,
                                                   u16 (&As)[2][128 * 32],
                                                   u16 (&Bs)[2][128 * 32],
                                                   f32x4 (&acc)[4][4])
{
    const int tid = threadIdx.x;
    const int wv = tid >> 6, lane = tid & 63;
    const int l15 = lane & 15, quad = lane >> 4;
    const int wr = wv >> 1, wc = wv & 1;

#pragma unroll
    for (int mt = 0; mt < 4; mt++)
#pragma unroll
        for (int nt = 0; nt < 4; nt++) acc[mt][nt] = (f32x4){0.f, 0.f, 0.f, 0.f};

    auto stage = [&](int k0, int buf) {
#pragma unroll
        for (int j = 0; j < 2; j++) {
            int c = wv * 128 + j * 64 + lane;
            const u16* ga = A + (size_t)(m0 + (c >> 2)) * 2048 + k0 + (c & 3) * 8;
            gload16(ga, &As[buf][(wv * 128 + j * 64) * 8]);
            const u16* gb = Bt + (size_t)(n0 + (c >> 2)) * 2048 + k0 + (c & 3) * 8;
            gload16(gb, &Bs[buf][(wv * 128 + j * 64) * 8]);
        }
    };

    stage(0, 0);
    __syncthreads();              // tile 0 staged (vmcnt drained)

    int cur = 0;
    for (int k0 = 0; k0 < 2048; k0 += 32) {
        if (k0 + 32 < 2048) stage(k0 + 32, cur ^ 1);   // prefetch hides under compute

        bf16x8 af[4], bfr[4];
#pragma unroll
        for (int mt = 0; mt < 4; mt++)
            af[mt] = *(const bf16x8*)&As[cur][(wr * 64 + mt * 16 + l15) * 32 + quad * 8];
#pragma unroll
        for (int nt = 0; nt < 4; nt++)
            bfr[nt] = *(const bf16x8*)&Bs[cur][(wc * 64 + nt * 16 + l15) * 32 + quad * 8];
#pragma unroll
        for (int mt = 0; mt < 4; mt++)
#pragma unroll
            for (int nt = 0; nt < 4; nt++)
                acc[mt][nt] = __builtin_amdgcn_mfma_f32_16x16x32_bf16(af[mt], bfr[nt], acc[mt][nt], 0, 0, 0);

        __syncthreads();          // next tile ready + all reads of cur done
        cur ^= 1;
    }
}

// Fused QKV: grid (24, 32), XCD-swizzled (768 = 8 * 96, bijective).
__global__ __launch_bounds__(256) void qkv_gemm_bf(const u16* __restrict__ Xq,
                                                   const u16* __restrict__ Xkv,
                                                   const u16* __restrict__ Wqt,
                                                   const u16* __restrict__ Wkt,
                                                   const u16* __restrict__ Wvt,
                                                   u16* __restrict__ qraw,
                                                   u16* __restrict__ kraw,
                                                   u16* __restrict__ vt)
{
    __shared__ __align__(16) u16 As[2][128 * 32];
    __shared__ __align__(16) u16 Bs[2][128 * 32];
    f32x4 acc[4][4];
    // XCD swizzle: round-robin XCD assignment (bid%8) gets contiguous work
    // chunks -> same-m0 panels cluster in one XCD's L2.
    const int bid0 = (int)blockIdx.x + 24 * (int)blockIdx.y;
    const int swz  = (bid0 & 7) * 96 + (bid0 >> 3);
    const int bx   = swz % 24;
    const int m0   = (swz / 24) * 128;
    const u16 *A, *Bt; int n0;
    if (bx < 16)      { A = Xq;  Bt = Wqt; n0 = bx * 128; }
    else if (bx < 20) { A = Xkv; Bt = Wkt; n0 = (bx - 16) * 128; }
    else              { A = Xkv; Bt = Wvt; n0 = (bx - 20) * 128; }
    bf16_gemm_mainloop(A, Bt, m0, n0, As, Bs, acc);

    const int tid = threadIdx.x;
    const int wv = tid >> 6, lane = tid & 63;
    const int l15 = lane & 15, quad = lane >> 4;
    const int wr = wv >> 1, wc = wv & 1;

    if (bx < 20) {
        u16* out; int ldw;
        if (bx < 16) { out = qraw; ldw = 2048; }
        else         { out = kraw; ldw = 512; }
#pragma unroll
        for (int mt = 0; mt < 4; mt++)
#pragma unroll
            for (int nt = 0; nt < 4; nt++) {
                int col = n0 + wc * 64 + nt * 16 + l15;
                int r = m0 + wr * 64 + mt * 16 + quad * 4;
#pragma unroll
                for (int reg = 0; reg < 4; reg++)
                    out[(size_t)(r + reg) * ldw + col] = f2bf(acc[mt][nt][reg]);
            }
    } else {
        const int b = m0 >> 11, tb = m0 & 2047;
#pragma unroll
        for (int mt = 0; mt < 4; mt++)
#pragma unroll
            for (int nt = 0; nt < 4; nt++) {
                int col = n0 + wc * 64 + nt * 16 + l15;
                int tloc = tb + wr * 64 + mt * 16 + quad * 4;
                ushort4 w4;
                w4.x = f2bf(acc[mt][nt][0]);
                w4.y = f2bf(acc[mt][nt][1]);
                w4.z = f2bf(acc[mt][nt][2]);
                w4.w = f2bf(acc[mt][nt][3]);
                *(ushort4*)&vt[((size_t)b * 512 + col) * 2048 + tloc] = w4;
            }
    }
}

// Output projection: grid (16, 32), XCD-swizzled (512 = 8 * 64, bijective).
__global__ __launch_bounds__(256) void oproj_gemm_bf(const u16* __restrict__ attnb,
                                                     const u16* __restrict__ Wot,
                                                     float* __restrict__ out)
{
    __shared__ __align__(16) u16 As[2][128 * 32];
    __shared__ __align__(16) u16 Bs[2][128 * 32];
    f32x4 acc[4][4];
    const int bid0 = (int)blockIdx.x + 16 * (int)blockIdx.y;
    const int swz  = (bid0 & 7) * 64 + (bid0 >> 3);
    const int n0   = (swz & 15) * 128;
    const int m0   = (swz >> 4) * 128;
    bf16_gemm_mainloop(attnb, Wot, m0, n0, As, Bs, acc);
    const int tid = threadIdx.x;
    const int wv = tid >> 6, lane = tid & 63;
    const int l15 = lane & 15, quad = lane >> 4;
    const int wr = wv >> 1, wc = wv & 1;
#pragma unroll
    for (int mt = 0; mt < 4; mt++)
#pragma unroll
        for (int nt = 0; nt < 4; nt++) {
            int col = n0 + wc * 64 + nt * 16 + l15;
            int r = m0 + wr * 64 + mt * 16 + quad * 4;
#pragma unroll
            for (int reg = 0; reg < 4; reg++)
                out[(size_t)(r + reg) * 2048 + col] = acc[mt][nt][reg];
        }
}

// In-place RoPE on bf16 q/k. q additionally pre-scaled by SCALE*log2e so
// flash attention's softmax runs in the exp2 domain with no per-score mult.
__global__ __launch_bounds__(256) void rope_bf(u16* __restrict__ q,
                                               u16* __restrict__ k,
                                               const int* __restrict__ qpos,
                                               const int* __restrict__ kvpos)
{
    const int qTh = Bdim * Tdim * NHq * 16;
    int idx = blockIdx.x * 256 + threadIdx.x;
    u16* base; int h4; int pos; float osc;
    if (idx < qTh) {
        int rn = idx >> 4; h4 = (idx & 15) * 4;
        pos = qpos[rn >> 4];
        base = q + (size_t)rn * HD;
        osc = QPRESCALE;
    } else {
        int j = idx - qTh;
        int rn = j >> 4; h4 = (j & 15) * 4;
        pos = kvpos[rn >> 2];
        base = k + (size_t)rn * HD;
        osc = 1.0f;
    }
    ushort4 a = *(const ushort4*)&base[h4];
    ushort4 bvec = *(const ushort4*)&base[h4 + 64];
    u16 av[4] = {a.x, a.y, a.z, a.w};
    u16 bv[4] = {bvec.x, bvec.y, bvec.z, bvec.w};
#pragma unroll
    for (int j = 0; j < 4; j++) {
        float inv_ts = expf(-(float)(h4 + j) * 0.14391156831f);
        float ang = (float)pos * inv_ts;
        float s, c;
        sincosf(ang, &s, &c);
        s *= osc; c *= osc;
        float x1 = bf2f(av[j]), x2 = bf2f(bv[j]);
        av[j] = f2bf(x1 * c - x2 * s);
        bv[j] = f2bf(x2 * c + x1 * s);
    }
    ushort4 ra, rb;
    ra.x = av[0]; ra.y = av[1]; ra.z = av[2]; ra.w = av[3];
    rb.x = bv[0]; rb.y = bv[1]; rb.z = bv[2]; rb.w = bv[3];
    *(ushort4*)&base[h4] = ra;
    *(ushort4*)&base[h4 + 64] = rb;
}

// ---------------------------------------------------------------------------
// Flash attention v5: BQ=128 split over EIGHT waves (16 rows each), BKV=64.
// 512-thread blocks; LDS 80 KB -> 2 blocks/CU, 16 waves/CU = 4 waves/SIMD.
// ---------------------------------------------------------------------------
__global__ __launch_bounds__(512, 4) void flash_attn_v5(const u16* __restrict__ qh,
                                                        const u16* __restrict__ kh,
                                                        const u16* __restrict__ vtg,
                                                        u16* __restrict__ attnb)
{
    // Ks[buf][s][h]: chunk cb = c8 ^ (s&7); addr = s*128 + cb*8 + (h&7)
    __shared__ __align__(16) u16 Ks[2][64 * 128];
    // Vt[buf][h][s]: chunk cb = sb ^ (h&7); addr = h*64 + cb*8 + (s&7)
    __shared__ __align__(16) u16 Vt[2][128 * 64];
    // Ps[m][s]: chunk cb = sb ^ (m&7)
    __shared__ __align__(16) u16 Ps[128 * 64];

    const int yy = blockIdx.y;
    const int qt = (yy < 8) ? (15 - yy) : (yy - 8);   // balanced pairing
    const int bh = blockIdx.x;
    const int b = bh >> 4, n = bh & 15, kvh = n >> 2;
    const int q0 = qt * 128;
    const int tid = threadIdx.x;
    const int wv = tid >> 6, lane = tid & 63;          // wv in 0..7
    const int l15 = lane & 15, quad = lane >> 4;

    const size_t kbase = (size_t)(b * Tdim) * 512 + kvh * 128;
    const size_t vbase = ((size_t)(b * 512 + kvh * 128)) * 2048;
    const int nT = 2 * qt + 2;

    auto stage = [&](int t, int buf) {
        const int s0s = t * 64;
#pragma unroll
        for (int c = 0; c < 2; c++) {
            int j = c * 512 + tid;        // 0..1023
            int s = j >> 4;               // 0..63
            int c8 = (j & 15) ^ (s & 7);
            gload16(kh + kbase + (size_t)(s0s + s) * 512 + c8 * 8,
                    &Ks[buf][(c * 512 + wv * 64) * 8]);
            int h = j >> 3;               // 0..127
            int sb = (j & 7) ^ (h & 7);
            gload16(vtg + vbase + (size_t)h * 2048 + s0s + sb * 8,
                    &Vt[buf][(c * 512 + wv * 64) * 8]);
        }
    };

    // issue tile 0 staging first, overlap Q-frag loads with it
    stage(0, 0);

    // ---- Q fragments direct from global (B-operand: n=l15->m, k=quad*8+j->h) ----
    // wave owns 16 q rows: m_l = wv*16 + l15
    bf16x8 qfrag[4];
    {
        const size_t qbase = ((size_t)(b * Tdim + q0 + wv * 16)) * 2048 + n * 128;
#pragma unroll
        for (int kt = 0; kt < 4; kt++)
            qfrag[kt] = *(const bf16x8*)(qh + qbase + (size_t)l15 * 2048
                                          + kt * 32 + quad * 8);
    }

    f32x4 Oacc[8];
#pragma unroll
    for (int ht = 0; ht < 8; ht++) Oacc[ht] = (f32x4){0.f, 0.f, 0.f, 0.f};
    float mrow = NEG_INF;
    float lrow = 0.f;

    __syncthreads();   // tile 0 staged (vmcnt drained by syncthreads)

    int cur = 0;
    for (int t = 0; t < nT; t++) {
        const int s0 = t * 64;

        // ---- issue next tile's staging into the other buffer (latency hides
        //      under this tile's compute; drained at the end-of-iter barrier) ----
        if (t + 1 < nT) stage(t + 1, cur ^ 1);

        // ---- S^T = K Q^T : tiles nt (s) ----
        f32x4 S[4];
#pragma unroll
        for (int nt = 0; nt < 4; nt++) S[nt] = (f32x4){0.f, 0.f, 0.f, 0.f};
#pragma unroll
        for (int kt = 0; kt < 4; kt++) {
            bf16x8 kf[4];
#pragma unroll
            for (int nt = 0; nt < 4; nt++) {
                int s = nt * 16 + l15;
                int cb = (kt * 4 + quad) ^ (s & 7);
                kf[nt] = *(const bf16x8*)&Ks[cur][s * 128 + cb * 8];
            }
#pragma unroll
            for (int nt = 0; nt < 4; nt++)
                S[nt] = __builtin_amdgcn_mfma_f32_16x16x32_bf16(kf[nt], qfrag[kt], S[nt], 0, 0, 0);
        }

        // ---- online softmax, exp2 domain ----
        const bool domask = (t >= nT - 2);
        const int m_l = wv * 16 + l15;
        const int mg = q0 + m_l;
        float sv[16];
#pragma unroll
        for (int nt = 0; nt < 4; nt++)
#pragma unroll
            for (int r = 0; r < 4; r++) {
                float vv = S[nt][r];              // already scaled (q pre-scale)
                if (domask) {
                    int sg = s0 + nt * 16 + quad * 4 + r;
                    if (sg > mg) vv = NEG_INF;
                }
                sv[nt * 4 + r] = vv;
            }
        float mx = quad_reduce_max(tree_max16(sv));
        // T13 defer-max: if no row of this wave grew past THR, keep mOld
        const bool skip = __all(mx <= mrow + DEFER_THR);
        const float mNew = skip ? mrow : fmaxf(mrow, mx);
#pragma unroll
        for (int i = 0; i < 16; i++)
            sv[i] = __builtin_amdgcn_exp2f(sv[i] - mNew);   // masked -> 0
        // ---- early P write: LDS write latency overlaps the sum chain ----
#pragma unroll
        for (int nt = 0; nt < 4; nt++) {
            int sb = nt * 2 + (quad >> 1);
            int cb = sb ^ (m_l & 7);
            ushort4 pw;
            pw.x = f2bfn(sv[nt * 4 + 0]);
            pw.y = f2bfn(sv[nt * 4 + 1]);
            pw.z = f2bfn(sv[nt * 4 + 2]);
            pw.w = f2bfn(sv[nt * 4 + 3]);
            *(ushort4*)&Ps[m_l * 64 + cb * 8 + (quad & 1) * 4] = pw;
        }
        {
            float ps = quad_reduce_sum(tree_sum16(sv));
            if (skip) {
                lrow += ps;
            } else {
                float alpha = __builtin_amdgcn_exp2f(mrow - mNew);
                mrow = mNew;
                lrow = lrow * alpha + ps;
                // rescale O: lane needs alpha of rows quad*4+r (held by lane quad*4+r)
                float a0 = __shfl(alpha, quad * 4 + 0);
                float a1 = __shfl(alpha, quad * 4 + 1);
                float a2 = __shfl(alpha, quad * 4 + 2);
                float a3 = __shfl(alpha, quad * 4 + 3);
#pragma unroll
                for (int ht = 0; ht < 8; ht++) {
                    Oacc[ht][0] *= a0;
                    Oacc[ht][1] *= a1;
                    Oacc[ht][2] *= a2;
                    Oacc[ht][3] *= a3;
                }
            }
        }

        // ---- O += P V ----
#pragma unroll
        for (int k2 = 0; k2 < 2; k2++) {
            int cbp = (k2 * 4 + quad) ^ (m_l & 7);
            bf16x8 pf = *(const bf16x8*)&Ps[m_l * 64 + cbp * 8];
#pragma unroll
            for (int ht = 0; ht < 8; ht++) {
                int h = ht * 16 + l15;
                int cb = (k2 * 4 + quad) ^ (h & 7);
                bf16x8 vf = *(const bf16x8*)&Vt[cur][h * 64 + cb * 8];
                Oacc[ht] = __builtin_amdgcn_mfma_f32_16x16x32_bf16(pf, vf, Oacc[ht], 0, 0, 0);
            }
        }

        __syncthreads();   // drains next-tile vmcnt + all waves done reading buf[cur]
        cur ^= 1;
    }

    // ---- epilogue: l broadcast via shfl (row quad*4+r held by lane quad*4+r) ----
    {
        f32x4 inv;
#pragma unroll
        for (int r = 0; r < 4; r++)
            inv[r] = 1.0f / __shfl(lrow, quad * 4 + r);
        int mg0 = q0 + wv * 16 + quad * 4;
        u16* dst0 = attnb + ((size_t)(b * Tdim + mg0)) * 2048 + n * 128 + l15;
#pragma unroll
        for (int ht = 0; ht < 8; ht++) {
#pragma unroll
            for (int r = 0; r < 4; r++)
                dst0[(size_t)r * 2048 + ht * 16] = f2bfn(Oacc[ht][r] * inv[r]);
        }
    }
}

extern "C" void kernel_launch(void* const* d_in, const int* in_sizes, int n_in,
                              void* d_out, int out_size, void* d_ws, size_t ws_size,
                              hipStream_t stream) {
    const float* Xq    = (const float*)d_in[0];
    const float* Xkv   = (const float*)d_in[1];
    const int*   qpos  = (const int*)d_in[2];
    const int*   kvpos = (const int*)d_in[3];
    const float* Wq    = (const float*)d_in[4];
    const float* Wk    = (const float*)d_in[5];
    const float* Wv    = (const float*)d_in[6];
    const float* Wo    = (const float*)d_in[7];
    float* out = (float*)d_out;

    char* w = (char*)d_ws;
    u16* xq_bf = (u16*)(w);                    // 16 MB
    u16* xkv_bf= (u16*)(w + (16u << 20));      // 16 MB
    u16* qraw  = (u16*)(w + (32u << 20));      // 16 MB (roped in place)
    u16* kraw  = (u16*)(w + (48u << 20));      //  4 MB (roped in place)
    u16* vt    = (u16*)(w + (52u << 20));      //  4 MB [(b*4+kvh)*128+h][2048]
    u16* wq_t  = (u16*)(w + (56u << 20));      //  8 MB
    u16* wk_t  = (u16*)(w + (64u << 20));      //  2 MB
    u16* wv_t  = (u16*)(w + (66u << 20));      //  2 MB
    u16* wo_t  = (u16*)(w + (68u << 20));      //  8 MB
    u16* attnb = (u16*)(w);                    // aliases xq_bf (dead by then)

    cvt_x<<<8192, 256, 0, stream>>>(Xq, Xkv, xq_bf, xkv_bf);
    cvt_w_t<<<dim3(32, 32), 256, 0, stream>>>(Wq, wq_t, 2048, 2048);
    cvt_w_t<<<dim3(8, 32),  256, 0, stream>>>(Wk, wk_t, 2048, 512);
    cvt_w_t<<<dim3(8, 32),  256, 0, stream>>>(Wv, wv_t, 2048, 512);
    cvt_w_t<<<dim3(32, 32), 256, 0, stream>>>(Wo, wo_t, 2048, 2048);
    qkv_gemm_bf<<<dim3(24, 32), 256, 0, stream>>>(xq_bf, xkv_bf, wq_t, wk_t, wv_t,
                                                  qraw, kraw, vt);
    rope_bf<<<5120, 256, 0, stream>>>(qraw, kraw, qpos, kvpos);
    flash_attn_v5<<<dim3(32, 16), 512, 0, stream>>>(qraw, kraw, vt, attnb);
    oproj_gemm_bf<<<dim3(16, 32), 256, 0, stream>>>(attnb, wo_t, out);
}

// Round 5
// 349.085 us; speedup vs baseline: 1.1777x; 1.0131x over previous
//
#include <hip/hip_runtime.h>
#include <hip/hip_bf16.h>
#include <cstdint>
#include <cstddef>

#define Bdim 2
#define Tdim 2048
#define Ddim 2048
#define NHq  16
#define NKV  4
#define HD   128
#define SCALE 0.08838834764831845f
// SCALE * log2(e): folded into q inside rope_bf so attention works in exp2 domain
#define QPRESCALE (0.08838834764831845f * 1.4426950408889634f)
#define NEG_INF (-3.0e38f)
// defer-max threshold (log2 domain): e-domain 8 -> 8*log2e ~ 11.5
#define DEFER_THR 11.5f

typedef unsigned short u16;
typedef unsigned int   u32;
typedef __bf16 bf16x8 __attribute__((ext_vector_type(8)));
typedef float  f32x4  __attribute__((ext_vector_type(4)));

__device__ __forceinline__ u16 f2bf(float f) {
    unsigned int u = __float_as_uint(f);
    u += 0x7FFFu + ((u >> 16) & 1u);   // RNE
    return (u16)(u >> 16);
}
__device__ __forceinline__ u16 f2bfn(float f) {
    __bf16 h = (__bf16)f;
    return __builtin_bit_cast(u16, h);
}
__device__ __forceinline__ float bf2f(u16 s) {
    return __uint_as_float(((unsigned int)s) << 16);
}

#if __has_builtin(__builtin_amdgcn_permlane16_swap) && __has_builtin(__builtin_amdgcn_permlane32_swap)
#define HAVE_PERMLANE_SWAP 1
#endif

__device__ __forceinline__ float quad_reduce_max(float v) {
#ifdef HAVE_PERMLANE_SWAP
    auto r = __builtin_amdgcn_permlane16_swap(__float_as_uint(v), __float_as_uint(v), false, false);
    float m = fmaxf(__uint_as_float(r[0]), __uint_as_float(r[1]));
    auto r2 = __builtin_amdgcn_permlane32_swap(__float_as_uint(m), __float_as_uint(m), false, false);
    return fmaxf(__uint_as_float(r2[0]), __uint_as_float(r2[1]));
#else
    v = fmaxf(v, __shfl_xor(v, 16));
    return fmaxf(v, __shfl_xor(v, 32));
#endif
}
__device__ __forceinline__ float quad_reduce_sum(float v) {
#ifdef HAVE_PERMLANE_SWAP
    auto r = __builtin_amdgcn_permlane16_swap(__float_as_uint(v), __float_as_uint(v), false, false);
    float s = __uint_as_float(r[0]) + __uint_as_float(r[1]);
    auto r2 = __builtin_amdgcn_permlane32_swap(__float_as_uint(s), __float_as_uint(s), false, false);
    return __uint_as_float(r2[0]) + __uint_as_float(r2[1]);
#else
    v += __shfl_xor(v, 16);
    return v + __shfl_xor(v, 32);
#endif
}

__device__ __forceinline__ float tree_max16(const float (&s)[16]) {
    float a0 = fmaxf(s[0], s[1]),  a1 = fmaxf(s[2], s[3]);
    float a2 = fmaxf(s[4], s[5]),  a3 = fmaxf(s[6], s[7]);
    float a4 = fmaxf(s[8], s[9]),  a5 = fmaxf(s[10], s[11]);
    float a6 = fmaxf(s[12], s[13]), a7 = fmaxf(s[14], s[15]);
    float b0 = fmaxf(a0, a1), b1 = fmaxf(a2, a3);
    float b2 = fmaxf(a4, a5), b3 = fmaxf(a6, a7);
    return fmaxf(fmaxf(b0, b1), fmaxf(b2, b3));
}
__device__ __forceinline__ float tree_sum16(const float (&s)[16]) {
    float a0 = s[0] + s[1],  a1 = s[2] + s[3];
    float a2 = s[4] + s[5],  a3 = s[6] + s[7];
    float a4 = s[8] + s[9],  a5 = s[10] + s[11];
    float a6 = s[12] + s[13], a7 = s[14] + s[15];
    float b0 = a0 + a1, b1 = a2 + a3, b2 = a4 + a5, b3 = a6 + a7;
    return (b0 + b1) + (b2 + b3);
}

// async global->LDS, 16B per lane. LDS dest is wave-uniform base + lane*16.
typedef __attribute__((address_space(1))) const u32 gbl_u32;
typedef __attribute__((address_space(3))) u32 lds_u32;
__device__ __forceinline__ void gload16(const void* g, void* l) {
    __builtin_amdgcn_global_load_lds((gbl_u32*)(uintptr_t)g, (lds_u32*)(uintptr_t)l, 16, 0, 0);
}

#define VM8 asm volatile("s_waitcnt vmcnt(8)" ::: "memory")
#define VM4 asm volatile("s_waitcnt vmcnt(4)" ::: "memory")
#define VM0 asm volatile("s_waitcnt vmcnt(0)" ::: "memory")
#define VMNONE ((void)0)
#define BARRIER do { asm volatile("" ::: "memory"); __builtin_amdgcn_s_barrier(); asm volatile("" ::: "memory"); } while (0)

// ---------------------------------------------------------------------------
// fp32 -> bf16 straight convert for Xq, Xkv. 8 elems/thread.
// ---------------------------------------------------------------------------
__global__ __launch_bounds__(256) void cvt_x(const float* __restrict__ Xq,
                                             const float* __restrict__ Xkv,
                                             u16* __restrict__ oq,
                                             u16* __restrict__ okv)
{
    const size_t NE = (size_t)4096 * 2048 / 8;
    size_t idx = (size_t)blockIdx.x * 256 + threadIdx.x;
    const float* src; u16* dst; size_t off;
    if (idx < NE) { src = Xq;  dst = oq;  off = idx * 8; }
    else          { src = Xkv; dst = okv; off = (idx - NE) * 8; }
    float4 a = *(const float4*)&src[off];
    float4 b = *(const float4*)&src[off + 4];
    ushort4 r0, r1;
    r0.x = f2bf(a.x); r0.y = f2bf(a.y); r0.z = f2bf(a.z); r0.w = f2bf(a.w);
    r1.x = f2bf(b.x); r1.y = f2bf(b.y); r1.z = f2bf(b.z); r1.w = f2bf(b.w);
    *(ushort4*)&dst[off] = r0;
    *(ushort4*)&dst[off + 4] = r1;
}

// ---------------------------------------------------------------------------
// fp32 W[R][C] -> bf16 W^T[C][R], 64x64 LDS tiles. grid (C/64, R/64).
// ---------------------------------------------------------------------------
__global__ __launch_bounds__(256) void cvt_w_t(const float* __restrict__ src,
                                               u16* __restrict__ dst, int R, int C)
{
    __shared__ u16 t[64][72];
    const int r0 = blockIdx.y * 64, c0 = blockIdx.x * 64;
    const int tid = threadIdx.x;
    const int tr = tid >> 4, tc4 = (tid & 15) * 4;
#pragma unroll
    for (int p = 0; p < 4; p++) {
        int r = p * 16 + tr;
        float4 v = *(const float4*)&src[(size_t)(r0 + r) * C + c0 + tc4];
        t[tc4 + 0][r] = f2bf(v.x);
        t[tc4 + 1][r] = f2bf(v.y);
        t[tc4 + 2][r] = f2bf(v.z);
        t[tc4 + 3][r] = f2bf(v.w);
    }
    __syncthreads();
#pragma unroll
    for (int p = 0; p < 4; p++) {
        int cc = p * 16 + tr;
        ushort4 w = *(const ushort4*)&t[cc][tc4];
        *(ushort4*)&dst[(size_t)(c0 + cc) * R + r0 + tc4] = w;
    }
}

// ---------------------------------------------------------------------------
// 8-phase 256x256 bf16 GEMM mainloop (HK-style schedule, plain HIP).
// BK=64 split in 2 khalves of 32 cols. LDS [buf][khalf][256 rows][32 cols],
// chunk-swizzled: 16B chunk c4 at row r lives at c4 ^ (r&3).
// 8 waves (2M x 4N), per-wave 128x64, acc[8][4]. 512 threads.
// Per phase: {4-8 ds_read_b128 || 1 half-slab stage (2 gload_lds)} ; barrier;
// lgkmcnt(0); setprio(1); 16 MFMA; setprio(0); [vmcnt(8) even phases]; barrier.
// Stages: P1/P2 -> cur buf1 tile ks1 (read at P7/P8); P3-P6 -> next buf0 tile;
// P7/P8 -> next buf1 tile ks0. vmcnt(8) at P2/P4/P6/P8 lands exactly the
// slabs read 1-2 phases later (counted, never 0 in steady state).
// ---------------------------------------------------------------------------
#define GPH(c, ks, mh, STAGE, VMW) do {                                        \
    bf16x8 Af[4];                                                              \
    _Pragma("unroll")                                                          \
    for (int mf = 0; mf < 4; mf++)                                             \
        Af[mf] = *(const bf16x8*)&Ab[c][ks][(arow + (mh) * 64 + mf * 16) * 32 + cxs]; \
    if ((mh) == 0) {                                                           \
        _Pragma("unroll")                                                      \
        for (int nf = 0; nf < 4; nf++)                                         \
            Bf[nf] = *(const bf16x8*)&Bb[c][ks][(brow + nf * 16) * 32 + cxs];  \
    }                                                                          \
    STAGE;                                                                     \
    BARRIER;                                                                   \
    asm volatile("s_waitcnt lgkmcnt(0)" ::: "memory");                         \
    __builtin_amdgcn_s_setprio(1);                                             \
    _Pragma("unroll")                                                          \
    for (int mf = 0; mf < 4; mf++)                                             \
        _Pragma("unroll")                                                      \
        for (int nf = 0; nf < 4; nf++)                                         \
            acc[(mh) * 4 + mf][nf] = __builtin_amdgcn_mfma_f32_16x16x32_bf16(  \
                Af[mf], Bf[nf], acc[(mh) * 4 + mf][nf], 0, 0, 0);              \
    __builtin_amdgcn_s_setprio(0);                                             \
    VMW;                                                                       \
    BARRIER;                                                                   \
} while (0)

__device__ __forceinline__ void gemm8_mainloop(const u16* __restrict__ A,
                                               const u16* __restrict__ Bt,
                                               int m0, int n0,
                                               u16 (&Ab)[2][2][256 * 32],
                                               u16 (&Bb)[2][2][256 * 32],
                                               f32x4 (&acc)[8][4])
{
    const int tid = threadIdx.x;
    const int wv = tid >> 6, lane = tid & 63;
    const int l15 = lane & 15, quad = lane >> 4;
    const int wr = wv >> 2, wc = wv & 3;

#pragma unroll
    for (int mf = 0; mf < 8; mf++)
#pragma unroll
        for (int nf = 0; nf < 4; nf++) acc[mf][nf] = (f32x4){0.f, 0.f, 0.f, 0.f};

    // stage one half-slab (256 rows x 32 cols) = 2 gload16/thread.
    // source col chunk pre-swizzled: c4 ^ (r&3); LDS dest linear.
    auto stageA = [&](int kt, int kh, int c) {
#pragma unroll
        for (int j = 0; j < 2; j++) {
            int q = j * 512 + tid;
            int r = q >> 2;
            int c4 = (q & 3) ^ (r & 3);
            gload16(A + (size_t)(m0 + r) * 2048 + kt * 64 + kh * 32 + c4 * 8,
                    &Ab[c][kh][q * 8]);
        }
    };
    auto stageB = [&](int kt, int kh, int c) {
#pragma unroll
        for (int j = 0; j < 2; j++) {
            int q = j * 512 + tid;
            int r = q >> 2;
            int c4 = (q & 3) ^ (r & 3);
            gload16(Bt + (size_t)(n0 + r) * 2048 + kt * 64 + kh * 32 + c4 * 8,
                    &Bb[c][kh][q * 8]);
        }
    };

    // frag read addressing: row & 3 == l15 & 3 for all frags
    const int arow = wr * 128 + l15;
    const int brow = wc * 64 + l15;
    const int cxs  = (quad ^ (l15 & 3)) * 8;

    // prologue: tile0 full @buf0, tile1 ks0 @buf1 (6 stages, 12 loads)
    stageA(0, 0, 0); stageB(0, 0, 0);
    stageA(0, 1, 0); stageB(0, 1, 0);
    stageA(1, 0, 1); stageB(1, 0, 1);
    VM8;      // tile0 ks0 (A+B) landed
    BARRIER;

    bf16x8 Bf[4];
    // main: 15 iters x 2 K-tiles; tiles t0=2*it (buf0), t1=2*it+1 (buf1)
    for (int it = 0; it < 15; it++) {
        const int t0 = 2 * it, t1 = 2 * it + 1;
        GPH(0, 0, 0, { stageA(t1, 1, 1); },     VMNONE);  // P1
        GPH(0, 0, 1, { stageB(t1, 1, 1); },     VM8);     // P2
        GPH(0, 1, 0, { stageA(t0 + 2, 0, 0); }, VMNONE);  // P3
        GPH(0, 1, 1, { stageB(t0 + 2, 0, 0); }, VM8);     // P4
        GPH(1, 0, 0, { stageA(t0 + 2, 1, 0); }, VMNONE);  // P5
        GPH(1, 0, 1, { stageB(t0 + 2, 1, 0); }, VM8);     // P6
        GPH(1, 1, 0, { stageA(t1 + 2, 0, 1); }, VMNONE);  // P7
        GPH(1, 1, 1, { stageB(t1 + 2, 0, 1); }, VM8);     // P8
    }
    // tail: tiles 30 (buf0), 31 (buf1); only tile31-ks1 left to stage
    GPH(0, 0, 0, { stageA(31, 1, 1); }, VMNONE);
    GPH(0, 0, 1, { stageB(31, 1, 1); }, VM8);
    GPH(0, 1, 0, VMNONE, VMNONE);
    GPH(0, 1, 1, VMNONE, VM4);
    GPH(1, 0, 0, VMNONE, VMNONE);
    GPH(1, 0, 1, VMNONE, VM0);
    GPH(1, 1, 0, VMNONE, VMNONE);
    GPH(1, 1, 1, VMNONE, VMNONE);
}

// Fused QKV, 8-phase: grid (12, 16) = 192 blocks (XCD-swizzled, 192%8==0).
// col tiles: 0-7 q, 8-9 k, 10-11 v.
__global__ __launch_bounds__(512, 2) void qkv_gemm8(const u16* __restrict__ Xq,
                                                    const u16* __restrict__ Xkv,
                                                    const u16* __restrict__ Wqt,
                                                    const u16* __restrict__ Wkt,
                                                    const u16* __restrict__ Wvt,
                                                    u16* __restrict__ qraw,
                                                    u16* __restrict__ kraw,
                                                    u16* __restrict__ vt)
{
    __shared__ __align__(16) u16 Ab[2][2][256 * 32];
    __shared__ __align__(16) u16 Bb[2][2][256 * 32];
    f32x4 acc[8][4];

    const int bid0 = (int)blockIdx.x + 12 * (int)blockIdx.y;
    const int swz  = (bid0 & 7) * 24 + (bid0 >> 3);
    const int cx   = swz % 12;
    const int m0   = (swz / 12) * 256;

    const u16 *A, *Bt; int nb;
    if (cx < 8)       { A = Xq;  Bt = Wqt; nb = cx * 256; }
    else if (cx < 10) { A = Xkv; Bt = Wkt; nb = (cx - 8) * 256; }
    else              { A = Xkv; Bt = Wvt; nb = (cx - 10) * 256; }

    gemm8_mainloop(A, Bt, m0, nb, Ab, Bb, acc);

    const int tid = threadIdx.x;
    const int wv = tid >> 6, lane = tid & 63;
    const int l15 = lane & 15, quad = lane >> 4;
    const int wr = wv >> 2, wc = wv & 3;
    const int row0 = m0 + wr * 128;

    if (cx < 10) {
        u16* out; int ldw;
        if (cx < 8) { out = qraw; ldw = 2048; }
        else        { out = kraw; ldw = 512; }
#pragma unroll
        for (int mf = 0; mf < 8; mf++)
#pragma unroll
            for (int nf = 0; nf < 4; nf++) {
                int col = nb + wc * 64 + nf * 16 + l15;
                int r = row0 + mf * 16 + quad * 4;
#pragma unroll
                for (int reg = 0; reg < 4; reg++)
                    out[(size_t)(r + reg) * ldw + col] = f2bf(acc[mf][nf][reg]);
            }
    } else {
        const int b = m0 >> 11;
#pragma unroll
        for (int mf = 0; mf < 8; mf++)
#pragma unroll
            for (int nf = 0; nf < 4; nf++) {
                int col = nb + wc * 64 + nf * 16 + l15;
                int tloc = ((row0 & 2047) + mf * 16 + quad * 4);
                ushort4 w4;
                w4.x = f2bf(acc[mf][nf][0]);
                w4.y = f2bf(acc[mf][nf][1]);
                w4.z = f2bf(acc[mf][nf][2]);
                w4.w = f2bf(acc[mf][nf][3]);
                *(ushort4*)&vt[((size_t)(b * 512 + col)) * 2048 + tloc] = w4;
            }
    }
}

// Output projection, 8-phase: grid (8, 16) = 128 blocks (XCD-swizzled).
__global__ __launch_bounds__(512, 2) void oproj_gemm8(const u16* __restrict__ attnb,
                                                      const u16* __restrict__ Wot,
                                                      float* __restrict__ out)
{
    __shared__ __align__(16) u16 Ab[2][2][256 * 32];
    __shared__ __align__(16) u16 Bb[2][2][256 * 32];
    f32x4 acc[8][4];

    const int bid0 = (int)blockIdx.x + 8 * (int)blockIdx.y;
    const int swz  = (bid0 & 7) * 16 + (bid0 >> 3);
    const int n0   = (swz % 8) * 256;
    const int m0   = (swz / 8) * 256;

    gemm8_mainloop(attnb, Wot, m0, n0, Ab, Bb, acc);

    const int tid = threadIdx.x;
    const int wv = tid >> 6, lane = tid & 63;
    const int l15 = lane & 15, quad = lane >> 4;
    const int wr = wv >> 2, wc = wv & 3;
    const int row0 = m0 + wr * 128;
#pragma unroll
    for (int mf = 0; mf < 8; mf++)
#pragma unroll
        for (int nf = 0; nf < 4; nf++) {
            int col = n0 + wc * 64 + nf * 16 + l15;
            int r = row0 + mf * 16 + quad * 4;
#pragma unroll
            for (int reg = 0; reg < 4; reg++)
                out[(size_t)(r + reg) * 2048 + col] = acc[mf][nf][reg];
        }
}

// In-place RoPE on bf16 q/k. q additionally pre-scaled by SCALE*log2e so
// flash attention's softmax runs in the exp2 domain with no per-score mult.
__global__ __launch_bounds__(256) void rope_bf(u16* __restrict__ q,
                                               u16* __restrict__ k,
                                               const int* __restrict__ qpos,
                                               const int* __restrict__ kvpos)
{
    const int qTh = Bdim * Tdim * NHq * 16;
    int idx = blockIdx.x * 256 + threadIdx.x;
    u16* base; int h4; int pos; float osc;
    if (idx < qTh) {
        int rn = idx >> 4; h4 = (idx & 15) * 4;
        pos = qpos[rn >> 4];
        base = q + (size_t)rn * HD;
        osc = QPRESCALE;
    } else {
        int j = idx - qTh;
        int rn = j >> 4; h4 = (j & 15) * 4;
        pos = kvpos[rn >> 2];
        base = k + (size_t)rn * HD;
        osc = 1.0f;
    }
    ushort4 a = *(const ushort4*)&base[h4];
    ushort4 bvec = *(const ushort4*)&base[h4 + 64];
    u16 av[4] = {a.x, a.y, a.z, a.w};
    u16 bv[4] = {bvec.x, bvec.y, bvec.z, bvec.w};
#pragma unroll
    for (int j = 0; j < 4; j++) {
        float inv_ts = expf(-(float)(h4 + j) * 0.14391156831f);
        float ang = (float)pos * inv_ts;
        float s, c;
        sincosf(ang, &s, &c);
        s *= osc; c *= osc;
        float x1 = bf2f(av[j]), x2 = bf2f(bv[j]);
        av[j] = f2bf(x1 * c - x2 * s);
        bv[j] = f2bf(x2 * c + x1 * s);
    }
    ushort4 ra, rb;
    ra.x = av[0]; ra.y = av[1]; ra.z = av[2]; ra.w = av[3];
    rb.x = bv[0]; rb.y = bv[1]; rb.z = bv[2]; rb.w = bv[3];
    *(ushort4*)&base[h4] = ra;
    *(ushort4*)&base[h4 + 64] = rb;
}

// ---------------------------------------------------------------------------
// Flash attention v5: BQ=128 split over EIGHT waves (16 rows each), BKV=64.
// 512-thread blocks; LDS 80 KB -> 2 blocks/CU, 16 waves/CU = 4 waves/SIMD.
// ---------------------------------------------------------------------------
__global__ __launch_bounds__(512, 4) void flash_attn_v5(const u16* __restrict__ qh,
                                                        const u16* __restrict__ kh,
                                                        const u16* __restrict__ vtg,
                                                        u16* __restrict__ attnb)
{
    __shared__ __align__(16) u16 Ks[2][64 * 128];
    __shared__ __align__(16) u16 Vt[2][128 * 64];
    __shared__ __align__(16) u16 Ps[128 * 64];

    const int yy = blockIdx.y;
    const int qt = (yy < 8) ? (15 - yy) : (yy - 8);   // balanced pairing
    const int bh = blockIdx.x;
    const int b = bh >> 4, n = bh & 15, kvh = n >> 2;
    const int q0 = qt * 128;
    const int tid = threadIdx.x;
    const int wv = tid >> 6, lane = tid & 63;          // wv in 0..7
    const int l15 = lane & 15, quad = lane >> 4;

    const size_t kbase = (size_t)(b * Tdim) * 512 + kvh * 128;
    const size_t vbase = ((size_t)(b * 512 + kvh * 128)) * 2048;
    const int nT = 2 * qt + 2;

    auto stage = [&](int t, int buf) {
        const int s0s = t * 64;
#pragma unroll
        for (int c = 0; c < 2; c++) {
            int j = c * 512 + tid;        // 0..1023
            int s = j >> 4;               // 0..63
            int c8 = (j & 15) ^ (s & 7);
            gload16(kh + kbase + (size_t)(s0s + s) * 512 + c8 * 8,
                    &Ks[buf][(c * 512 + wv * 64) * 8]);
            int h = j >> 3;               // 0..127
            int sb = (j & 7) ^ (h & 7);
            gload16(vtg + vbase + (size_t)h * 2048 + s0s + sb * 8,
                    &Vt[buf][(c * 512 + wv * 64) * 8]);
        }
    };

    stage(0, 0);

    bf16x8 qfrag[4];
    {
        const size_t qbase = ((size_t)(b * Tdim + q0 + wv * 16)) * 2048 + n * 128;
#pragma unroll
        for (int kt = 0; kt < 4; kt++)
            qfrag[kt] = *(const bf16x8*)(qh + qbase + (size_t)l15 * 2048
                                          + kt * 32 + quad * 8);
    }

    f32x4 Oacc[8];
#pragma unroll
    for (int ht = 0; ht < 8; ht++) Oacc[ht] = (f32x4){0.f, 0.f, 0.f, 0.f};
    float mrow = NEG_INF;
    float lrow = 0.f;

    __syncthreads();   // tile 0 staged

    int cur = 0;
    for (int t = 0; t < nT; t++) {
        const int s0 = t * 64;

        if (t + 1 < nT) stage(t + 1, cur ^ 1);

        f32x4 S[4];
#pragma unroll
        for (int nt = 0; nt < 4; nt++) S[nt] = (f32x4){0.f, 0.f, 0.f, 0.f};
#pragma unroll
        for (int kt = 0; kt < 4; kt++) {
            bf16x8 kf[4];
#pragma unroll
            for (int nt = 0; nt < 4; nt++) {
                int s = nt * 16 + l15;
                int cb = (kt * 4 + quad) ^ (s & 7);
                kf[nt] = *(const bf16x8*)&Ks[cur][s * 128 + cb * 8];
            }
#pragma unroll
            for (int nt = 0; nt < 4; nt++)
                S[nt] = __builtin_amdgcn_mfma_f32_16x16x32_bf16(kf[nt], qfrag[kt], S[nt], 0, 0, 0);
        }

        const bool domask = (t >= nT - 2);
        const int m_l = wv * 16 + l15;
        const int mg = q0 + m_l;
        float sv[16];
#pragma unroll
        for (int nt = 0; nt < 4; nt++)
#pragma unroll
            for (int r = 0; r < 4; r++) {
                float vv = S[nt][r];
                if (domask) {
                    int sg = s0 + nt * 16 + quad * 4 + r;
                    if (sg > mg) vv = NEG_INF;
                }
                sv[nt * 4 + r] = vv;
            }
        float mx = quad_reduce_max(tree_max16(sv));
        const bool skip = __all(mx <= mrow + DEFER_THR);
        const float mNew = skip ? mrow : fmaxf(mrow, mx);
#pragma unroll
        for (int i = 0; i < 16; i++)
            sv[i] = __builtin_amdgcn_exp2f(sv[i] - mNew);
#pragma unroll
        for (int nt = 0; nt < 4; nt++) {
            int sb = nt * 2 + (quad >> 1);
            int cb = sb ^ (m_l & 7);
            ushort4 pw;
            pw.x = f2bfn(sv[nt * 4 + 0]);
            pw.y = f2bfn(sv[nt * 4 + 1]);
            pw.z = f2bfn(sv[nt * 4 + 2]);
            pw.w = f2bfn(sv[nt * 4 + 3]);
            *(ushort4*)&Ps[m_l * 64 + cb * 8 + (quad & 1) * 4] = pw;
        }
        {
            float ps = quad_reduce_sum(tree_sum16(sv));
            if (skip) {
                lrow += ps;
            } else {
                float alpha = __builtin_amdgcn_exp2f(mrow - mNew);
                mrow = mNew;
                lrow = lrow * alpha + ps;
                float a0 = __shfl(alpha, quad * 4 + 0);
                float a1 = __shfl(alpha, quad * 4 + 1);
                float a2 = __shfl(alpha, quad * 4 + 2);
                float a3 = __shfl(alpha, quad * 4 + 3);
#pragma unroll
                for (int ht = 0; ht < 8; ht++) {
                    Oacc[ht][0] *= a0;
                    Oacc[ht][1] *= a1;
                    Oacc[ht][2] *= a2;
                    Oacc[ht][3] *= a3;
                }
            }
        }

#pragma unroll
        for (int k2 = 0; k2 < 2; k2++) {
            int cbp = (k2 * 4 + quad) ^ (m_l & 7);
            bf16x8 pf = *(const bf16x8*)&Ps[m_l * 64 + cbp * 8];
#pragma unroll
            for (int ht = 0; ht < 8; ht++) {
                int h = ht * 16 + l15;
                int cb = (k2 * 4 + quad) ^ (h & 7);
                bf16x8 vf = *(const bf16x8*)&Vt[cur][h * 64 + cb * 8];
                Oacc[ht] = __builtin_amdgcn_mfma_f32_16x16x32_bf16(pf, vf, Oacc[ht], 0, 0, 0);
            }
        }

        __syncthreads();
        cur ^= 1;
    }

    {
        f32x4 inv;
#pragma unroll
        for (int r = 0; r < 4; r++)
            inv[r] = 1.0f / __shfl(lrow, quad * 4 + r);
        int mg0 = q0 + wv * 16 + quad * 4;
        u16* dst0 = attnb + ((size_t)(b * Tdim + mg0)) * 2048 + n * 128 + l15;
#pragma unroll
        for (int ht = 0; ht < 8; ht++) {
#pragma unroll
            for (int r = 0; r < 4; r++)
                dst0[(size_t)r * 2048 + ht * 16] = f2bfn(Oacc[ht][r] * inv[r]);
        }
    }
}

extern "C" void kernel_launch(void* const* d_in, const int* in_sizes, int n_in,
                              void* d_out, int out_size, void* d_ws, size_t ws_size,
                              hipStream_t stream) {
    const float* Xq    = (const float*)d_in[0];
    const float* Xkv   = (const float*)d_in[1];
    const int*   qpos  = (const int*)d_in[2];
    const int*   kvpos = (const int*)d_in[3];
    const float* Wq    = (const float*)d_in[4];
    const float* Wk    = (const float*)d_in[5];
    const float* Wv    = (const float*)d_in[6];
    const float* Wo    = (const float*)d_in[7];
    float* out = (float*)d_out;

    char* w = (char*)d_ws;
    u16* xq_bf = (u16*)(w);                    // 16 MB
    u16* xkv_bf= (u16*)(w + (16u << 20));      // 16 MB
    u16* qraw  = (u16*)(w + (32u << 20));      // 16 MB (roped in place)
    u16* kraw  = (u16*)(w + (48u << 20));      //  4 MB (roped in place)
    u16* vt    = (u16*)(w + (52u << 20));      //  4 MB [(b*4+kvh)*128+h][2048]
    u16* wq_t  = (u16*)(w + (56u << 20));      //  8 MB
    u16* wk_t  = (u16*)(w + (64u << 20));      //  2 MB
    u16* wv_t  = (u16*)(w + (66u << 20));      //  2 MB
    u16* wo_t  = (u16*)(w + (68u << 20));      //  8 MB
    u16* attnb = (u16*)(w);                    // aliases xq_bf (dead by then)

    cvt_x<<<8192, 256, 0, stream>>>(Xq, Xkv, xq_bf, xkv_bf);
    cvt_w_t<<<dim3(32, 32), 256, 0, stream>>>(Wq, wq_t, 2048, 2048);
    cvt_w_t<<<dim3(8, 32),  256, 0, stream>>>(Wk, wk_t, 2048, 512);
    cvt_w_t<<<dim3(8, 32),  256, 0, stream>>>(Wv, wv_t, 2048, 512);
    cvt_w_t<<<dim3(32, 32), 256, 0, stream>>>(Wo, wo_t, 2048, 2048);
    qkv_gemm8<<<dim3(12, 16), 512, 0, stream>>>(xq_bf, xkv_bf, wq_t, wk_t, wv_t,
                                                qraw, kraw, vt);
    rope_bf<<<5120, 256, 0, stream>>>(qraw, kraw, qpos, kvpos);
    flash_attn_v5<<<dim3(32, 16), 512, 0, stream>>>(qraw, kraw, vt, attnb);
    oproj_gemm8<<<dim3(8, 16), 512, 0, stream>>>(attnb, wo_t, out);
}